// Round 1
// baseline (1657.152 us; speedup 1.0000x reference)
//
#include <hip/hip_runtime.h>
#include <stdint.h>

// Mamba forward, MI355X. Round 0: correctness-first full implementation.
// GEMMs: bf16 MFMA 16x16x32, 128x128 tile, 4 waves, reg-staged LDS (m93-class).
// Scan: 3-phase chunked linear scan (32 chunks x 64 steps).
// Workspace need: ~186 MB.

#define D_MODEL 768
#define N_LAYER 4
#define VOCAB 50257
#define VOCAB_PAD 50304   // 393*128
#define D_STATE 16
#define D_CONV 4
#define D_INNER 1536
#define DT_RANK 48
#define LSEQ 2048
#define TCHUNK 64
#define NCHUNK 32

typedef unsigned short u16;
typedef __attribute__((ext_vector_type(8))) short short8;
typedef __attribute__((ext_vector_type(8))) unsigned short ushort8;
typedef __attribute__((ext_vector_type(4))) float f32x4;

__device__ __forceinline__ u16 f2bf(float f) {
  unsigned int x = __float_as_uint(f);
  x += 0x7fffu + ((x >> 16) & 1u);   // RNE
  return (u16)(x >> 16);
}

// ---------------- conversion with zero padding (rows to Npad, cols to Kpad) --
__global__ void k_convert_pad(const float* __restrict__ src, u16* __restrict__ dst,
                              int N, int K, int Kpad, long total) {
  long i = (long)blockIdx.x * 256 + threadIdx.x;
  if (i >= total) return;
  int n = (int)(i / Kpad), k = (int)(i % Kpad);
  float v = (n < N && k < K) ? src[(long)n * K + k] : 0.0f;
  dst[i] = f2bf(v);
}

// ---------------- embedding gather (fp32) -----------------------------------
__global__ void k_embed(const int* __restrict__ idx, const float* __restrict__ emb,
                        float* __restrict__ x) {
  int i = blockIdx.x * 256 + threadIdx.x;   // L*D_MODEL threads
  int t = i / D_MODEL, c = i % D_MODEL;
  x[i] = emb[(long)idx[t] * D_MODEL + c];
}

// ---------------- rmsnorm -> bf16 -------------------------------------------
__global__ void k_rmsnorm_bf16(const float* __restrict__ x, const float* __restrict__ w,
                               u16* __restrict__ out) {
  int t = blockIdx.x, tid = threadIdx.x;
  __shared__ float red[256];
  const float* row = x + (long)t * D_MODEL;
  float s = 0.0f;
  for (int c = tid; c < D_MODEL; c += 256) { float v = row[c]; s += v * v; }
  red[tid] = s; __syncthreads();
  for (int o = 128; o > 0; o >>= 1) { if (tid < o) red[tid] += red[tid + o]; __syncthreads(); }
  float scale = rsqrtf(red[0] / (float)D_MODEL + 1e-5f);
  for (int c = tid; c < D_MODEL; c += 256) out[(long)t * D_MODEL + c] = f2bf(row[c] * scale * w[c]);
}

// ---------------- GEMM: C(M,N) fp32 = A(M,K)bf16 * W(N,K)bf16^T --------------
// M % 128 == 0 (always 2048), W padded to N multiple of 128 and K multiple of 32.
__global__ __launch_bounds__(256) void k_gemm_bt(
    const u16* __restrict__ A, const u16* __restrict__ W, float* __restrict__ C,
    int N, int K, int lda, int ldb, int ldc) {
  __shared__ u16 lA[128 * 32];
  __shared__ u16 lB[128 * 32];
  const int tid = threadIdx.x, wid = tid >> 6, lane = tid & 63;
  const int brow = blockIdx.y * 128, bcol = blockIdx.x * 128;
  const int wm = (wid >> 1) * 64, wn = (wid & 1) * 64;
  const int fr = lane & 15, fq = lane >> 4, kh = fq * 8;
  f32x4 acc[4][4];
#pragma unroll
  for (int i = 0; i < 4; i++)
#pragma unroll
    for (int j = 0; j < 4; j++)
#pragma unroll
      for (int r = 0; r < 4; r++) acc[i][j][r] = 0.0f;

  const int lrow = tid >> 2;          // 0..63
  const int lcol = (tid & 3) * 8;     // 0,8,16,24

  for (int k0 = 0; k0 < K; k0 += 32) {
#pragma unroll
    for (int h = 0; h < 2; ++h) {
      int r = lrow + h * 64;
      *(ushort8*)(&lA[r * 32 + lcol]) =
          *(const ushort8*)(A + (size_t)(brow + r) * lda + k0 + lcol);
      *(ushort8*)(&lB[r * 32 + lcol]) =
          *(const ushort8*)(W + (size_t)(bcol + r) * ldb + k0 + lcol);
    }
    __syncthreads();
    short8 af[4], bf[4];
#pragma unroll
    for (int i = 0; i < 4; i++) af[i] = *(const short8*)(&lA[(wm + i * 16 + fr) * 32 + kh]);
#pragma unroll
    for (int j = 0; j < 4; j++) bf[j] = *(const short8*)(&lB[(wn + j * 16 + fr) * 32 + kh]);
#pragma unroll
    for (int i = 0; i < 4; i++)
#pragma unroll
      for (int j = 0; j < 4; j++)
        acc[i][j] = __builtin_amdgcn_mfma_f32_16x16x32_bf16(af[i], bf[j], acc[i][j], 0, 0, 0);
    __syncthreads();
  }
  // C/D layout: col = lane&15, row = (lane>>4)*4 + reg  [guide §3, m89-verified]
#pragma unroll
  for (int i = 0; i < 4; i++)
#pragma unroll
    for (int j = 0; j < 4; j++) {
      int col = bcol + wn + j * 16 + fr;
      if (col < N) {
#pragma unroll
        for (int r = 0; r < 4; r++) {
          int row = brow + wm + i * 16 + fq * 4 + r;
          C[(size_t)row * ldc + col] = acc[i][j][r];
        }
      }
    }
}

// ---------------- causal conv1d (K=4) + silu --------------------------------
__global__ void k_conv_silu(const float* __restrict__ xz, const float* __restrict__ cw,
                            const float* __restrict__ cb, float* __restrict__ xif,
                            u16* __restrict__ xib) {
  int i = blockIdx.x * 256 + threadIdx.x;  // L*D_INNER
  int t = i / D_INNER, d = i % D_INNER;
  float acc = cb[d];
#pragma unroll
  for (int k = 0; k < 4; k++) {
    int tt = t - 3 + k;
    if (tt >= 0) acc += xz[(long)tt * (2 * D_INNER) + d] * cw[d * 4 + k];
  }
  float s = acc / (1.0f + __expf(-acc));
  xif[i] = s;
  xib[i] = f2bf(s);
}

// ---------------- dt slice of xdbl -> bf16 padded to 64 ---------------------
__global__ void k_dtpad(const float* __restrict__ xdbl, u16* __restrict__ dtp) {
  int i = blockIdx.x * 256 + threadIdx.x;  // L*64
  int t = i >> 6, k = i & 63;
  dtp[i] = (k < DT_RANK) ? f2bf(xdbl[(long)t * 80 + k]) : (u16)0;
}

// ---------------- softplus(dtl + b) in place ---------------------------------
__global__ void k_softplus(float* __restrict__ dtl, const float* __restrict__ b) {
  int i = blockIdx.x * 256 + threadIdx.x;  // L*D_INNER
  int d = i % D_INNER;
  float v = dtl[i] + b[d];
  dtl[i] = (v > 20.0f) ? v : log1pf(__expf(v));
}

// ---------------- selective scan: 3-phase chunked ----------------------------
__global__ void k_scanA(const float* __restrict__ dt, const float* __restrict__ xi,
                        const float* __restrict__ xdbl, const float* __restrict__ a_log,
                        float* __restrict__ aprod, float* __restrict__ hend) {
  int d = blockIdx.x * 256 + threadIdx.x;
  int c = blockIdx.y;
  float A[16], ap[16], h[16];
#pragma unroll
  for (int s = 0; s < 16; s++) { A[s] = -__expf(a_log[d * 16 + s]); ap[s] = 1.0f; h[s] = 0.0f; }
  int t0 = c * TCHUNK;
  for (int t = t0; t < t0 + TCHUNK; t++) {
    float dtv = dt[(long)t * D_INNER + d], xv = xi[(long)t * D_INNER + d];
    float dx = dtv * xv;
    const float* Bp = xdbl + (long)t * 80 + DT_RANK;
#pragma unroll
    for (int s = 0; s < 16; s++) {
      float a = __expf(dtv * A[s]);
      h[s] = a * h[s] + dx * Bp[s];
      ap[s] *= a;
    }
  }
  long base = ((long)c * D_INNER + d) * 16;
#pragma unroll
  for (int s = 0; s < 16; s++) { aprod[base + s] = ap[s]; hend[base + s] = h[s]; }
}

__global__ void k_scanB(const float* __restrict__ aprod, const float* __restrict__ hend,
                        float* __restrict__ hinit) {
  int i = blockIdx.x * 256 + threadIdx.x;  // D_INNER*16
  float h = 0.0f;
  for (int c = 0; c < NCHUNK; c++) {
    long idx = (long)c * D_INNER * 16 + i;
    hinit[idx] = h;
    h = aprod[idx] * h + hend[idx];
  }
}

__global__ void k_scanC(const float* __restrict__ dt, const float* __restrict__ xi,
                        const float* __restrict__ xdbl, const float* __restrict__ a_log,
                        const float* __restrict__ hinit, const float* __restrict__ Dp,
                        float* __restrict__ y) {
  int d = blockIdx.x * 256 + threadIdx.x;
  int c = blockIdx.y;
  float A[16], h[16];
  long hb = (long)c * D_INNER * 16 + (long)d * 16;
#pragma unroll
  for (int s = 0; s < 16; s++) { A[s] = -__expf(a_log[d * 16 + s]); h[s] = hinit[hb + s]; }
  float Dv = Dp[d];
  int t0 = c * TCHUNK;
  for (int t = t0; t < t0 + TCHUNK; t++) {
    float dtv = dt[(long)t * D_INNER + d], xv = xi[(long)t * D_INNER + d];
    float dx = dtv * xv;
    const float* Bp = xdbl + (long)t * 80 + DT_RANK;
    const float* Cp = Bp + D_STATE;
    float o = xv * Dv;
#pragma unroll
    for (int s = 0; s < 16; s++) {
      float a = __expf(dtv * A[s]);
      h[s] = a * h[s] + dx * Bp[s];
      o += h[s] * Cp[s];
    }
    y[(long)t * D_INNER + d] = o;
  }
}

// ---------------- y * silu(z) -> bf16 ----------------------------------------
__global__ void k_ymul(const float* __restrict__ y, const float* __restrict__ xz,
                       u16* __restrict__ yb) {
  int i = blockIdx.x * 256 + threadIdx.x;  // L*D_INNER
  int t = i / D_INNER, d = i % D_INNER;
  float z = xz[(long)t * (2 * D_INNER) + D_INNER + d];
  float v = y[i] * (z / (1.0f + __expf(-z)));
  yb[i] = f2bf(v);
}

// ---------------- residual add ----------------------------------------------
__global__ void k_add(float* __restrict__ x, const float* __restrict__ o) {
  int i = blockIdx.x * 256 + threadIdx.x;
  x[i] += o[i];
}

// ---------------- per-row logsumexp + nll ------------------------------------
__global__ void k_row_lse(const float* __restrict__ logits, const int* __restrict__ tgt,
                          float* __restrict__ nll, float* __restrict__ msk) {
  int t = blockIdx.x, tid = threadIdx.x;
  __shared__ float red[256];
  const float* row = logits + (size_t)t * VOCAB;
  float m = -1e30f;
  for (int c = tid; c < VOCAB; c += 256) m = fmaxf(m, row[c]);
  red[tid] = m; __syncthreads();
  for (int o = 128; o > 0; o >>= 1) { if (tid < o) red[tid] = fmaxf(red[tid], red[tid + o]); __syncthreads(); }
  float rm = red[0]; __syncthreads();
  float s = 0.0f;
  for (int c = tid; c < VOCAB; c += 256) s += __expf(row[c] - rm);
  red[tid] = s; __syncthreads();
  for (int o = 128; o > 0; o >>= 1) { if (tid < o) red[tid] += red[tid + o]; __syncthreads(); }
  if (tid == 0) {
    float lse = rm + __logf(red[0]);
    int tg = tgt[t];
    float mk = tg >= 0 ? 1.0f : 0.0f;
    int tc = tg < 0 ? 0 : (tg > VOCAB - 1 ? VOCAB - 1 : tg);
    nll[t] = (lse - row[tc]) * mk;
    msk[t] = mk;
  }
}

__global__ void k_loss(const float* __restrict__ nll, const float* __restrict__ msk,
                       float* __restrict__ out) {
  int tid = threadIdx.x;
  __shared__ float r1[256], r2[256];
  float a = 0.0f, b = 0.0f;
  for (int i = tid; i < LSEQ; i += 256) { a += nll[i]; b += msk[i]; }
  r1[tid] = a; r2[tid] = b; __syncthreads();
  for (int o = 128; o > 0; o >>= 1) {
    if (tid < o) { r1[tid] += r1[tid + o]; r2[tid] += r2[tid + o]; }
    __syncthreads();
  }
  if (tid == 0) out[0] = r1[0] / fmaxf(r2[0], 1.0f);
}

// =============================================================================
extern "C" void kernel_launch(void* const* d_in, const int* in_sizes, int n_in,
                              void* d_out, int out_size, void* d_ws, size_t ws_size,
                              hipStream_t stream) {
  const int*   idx    = (const int*)d_in[0];
  const int*   tgt    = (const int*)d_in[1];
  const float* emb    = (const float*)d_in[2];
  const float* norm_w = (const float*)d_in[3];
  const float* in_w   = (const float*)d_in[4];
  const float* conv_w = (const float*)d_in[5];
  const float* conv_b = (const float*)d_in[6];
  const float* xp_w   = (const float*)d_in[7];
  const float* dt_w   = (const float*)d_in[8];
  const float* dt_b   = (const float*)d_in[9];
  const float* a_log  = (const float*)d_in[10];
  const float* d_par  = (const float*)d_in[11];
  const float* out_w  = (const float*)d_in[12];
  const float* normf  = (const float*)d_in[13];

  float* logits = (float*)d_out;
  float* loss   = logits + (size_t)LSEQ * VOCAB;

  char* base = (char*)d_ws;
  size_t off = 0;
  auto alloc = [&](size_t bytes) -> char* {
    char* r = base + off;
    off = (off + bytes + 255) & ~(size_t)255;
    return r;
  };
  u16*   embb = (u16*)  alloc((size_t)VOCAB_PAD * D_MODEL * 2);
  float* x    = (float*)alloc((size_t)LSEQ * D_MODEL * 4);
  u16*   xnb  = (u16*)  alloc((size_t)LSEQ * D_MODEL * 2);
  float* xz   = (float*)alloc((size_t)LSEQ * 2 * D_INNER * 4);
  float* xif  = (float*)alloc((size_t)LSEQ * D_INNER * 4);
  u16*   xib  = (u16*)  alloc((size_t)LSEQ * D_INNER * 2);
  u16*   w1   = (u16*)  alloc((size_t)2 * D_INNER * D_MODEL * 2);
  u16*   w2   = (u16*)  alloc((size_t)128 * D_INNER * 2);
  u16*   w3   = (u16*)  alloc((size_t)D_INNER * 64 * 2);
  u16*   w4   = (u16*)  alloc((size_t)D_MODEL * D_INNER * 2);
  float* xdbl = (float*)alloc((size_t)LSEQ * 80 * 4);
  u16*   dtp  = (u16*)  alloc((size_t)LSEQ * 64 * 2);
  float* dtl  = (float*)alloc((size_t)LSEQ * D_INNER * 4);
  float* yv   = (float*)alloc((size_t)LSEQ * D_INNER * 4);
  u16*   yb   = (u16*)  alloc((size_t)LSEQ * D_INNER * 2);
  float* o4   = (float*)alloc((size_t)LSEQ * D_MODEL * 4);
  float* apr  = (float*)alloc((size_t)NCHUNK * D_INNER * 16 * 4);
  float* hen  = (float*)alloc((size_t)NCHUNK * D_INNER * 16 * 4);
  float* hin  = (float*)alloc((size_t)NCHUNK * D_INNER * 16 * 4);
  float* nll  = (float*)alloc((size_t)LSEQ * 4);
  float* msk  = (float*)alloc((size_t)LSEQ * 4);
  (void)ws_size; (void)in_sizes; (void)n_in; (void)out_size;

  // embedding: bf16 copy (padded rows) + fp32 gather
  {
    long tot = (long)VOCAB_PAD * D_MODEL;
    k_convert_pad<<<(unsigned)((tot + 255) / 256), 256, 0, stream>>>(emb, embb, VOCAB, D_MODEL, D_MODEL, tot);
  }
  k_embed<<<(LSEQ * D_MODEL) / 256, 256, 0, stream>>>(idx, emb, x);

  for (int l = 0; l < N_LAYER; l++) {
    k_rmsnorm_bf16<<<LSEQ, 256, 0, stream>>>(x, norm_w + l * D_MODEL, xnb);

    { long tot = (long)2 * D_INNER * D_MODEL;
      k_convert_pad<<<(unsigned)((tot + 255) / 256), 256, 0, stream>>>(
          in_w + (long)l * 2 * D_INNER * D_MODEL, w1, 2 * D_INNER, D_MODEL, D_MODEL, tot); }
    k_gemm_bt<<<dim3(2 * D_INNER / 128, LSEQ / 128), 256, 0, stream>>>(
        xnb, w1, xz, 2 * D_INNER, D_MODEL, D_MODEL, D_MODEL, 2 * D_INNER);

    k_conv_silu<<<(LSEQ * D_INNER) / 256, 256, 0, stream>>>(
        xz, conv_w + (long)l * D_INNER * 4, conv_b + l * D_INNER, xif, xib);

    { long tot = (long)128 * D_INNER;
      k_convert_pad<<<(unsigned)((tot + 255) / 256), 256, 0, stream>>>(
          xp_w + (long)l * 80 * D_INNER, w2, 80, D_INNER, D_INNER, tot); }
    k_gemm_bt<<<dim3(1, LSEQ / 128), 256, 0, stream>>>(
        xib, w2, xdbl, 80, D_INNER, D_INNER, D_INNER, 80);

    k_dtpad<<<(LSEQ * 64) / 256, 256, 0, stream>>>(xdbl, dtp);
    { long tot = (long)D_INNER * 64;
      k_convert_pad<<<(unsigned)((tot + 255) / 256), 256, 0, stream>>>(
          dt_w + (long)l * D_INNER * DT_RANK, w3, D_INNER, DT_RANK, 64, tot); }
    k_gemm_bt<<<dim3(D_INNER / 128, LSEQ / 128), 256, 0, stream>>>(
        dtp, w3, dtl, D_INNER, 64, 64, 64, D_INNER);
    k_softplus<<<(LSEQ * D_INNER) / 256, 256, 0, stream>>>(dtl, dt_b + l * D_INNER);

    const float* al = a_log + (long)l * D_INNER * D_STATE;
    k_scanA<<<dim3(D_INNER / 256, NCHUNK), 256, 0, stream>>>(dtl, xif, xdbl, al, apr, hen);
    k_scanB<<<(D_INNER * 16) / 256, 256, 0, stream>>>(apr, hen, hin);
    k_scanC<<<dim3(D_INNER / 256, NCHUNK), 256, 0, stream>>>(dtl, xif, xdbl, al, hin,
                                                             d_par + l * D_INNER, yv);

    k_ymul<<<(LSEQ * D_INNER) / 256, 256, 0, stream>>>(yv, xz, yb);

    { long tot = (long)D_MODEL * D_INNER;
      k_convert_pad<<<(unsigned)((tot + 255) / 256), 256, 0, stream>>>(
          out_w + (long)l * D_MODEL * D_INNER, w4, D_MODEL, D_INNER, D_INNER, tot); }
    k_gemm_bt<<<dim3(D_MODEL / 128, LSEQ / 128), 256, 0, stream>>>(
        yb, w4, o4, D_MODEL, D_INNER, D_INNER, D_INNER, D_MODEL);
    k_add<<<(LSEQ * D_MODEL) / 256, 256, 0, stream>>>(x, o4);
  }

  k_rmsnorm_bf16<<<LSEQ, 256, 0, stream>>>(x, normf, xnb);
  k_gemm_bt<<<dim3(VOCAB_PAD / 128, LSEQ / 128), 256, 0, stream>>>(
      xnb, embb, logits, VOCAB, D_MODEL, D_MODEL, D_MODEL, VOCAB);

  k_row_lse<<<LSEQ, 256, 0, stream>>>(logits, tgt, nll, msk);
  k_loss<<<1, 256, 0, stream>>>(nll, msk, loss);
}

// Round 2
// 1546.851 us; speedup vs baseline: 1.0713x; 1.0713x over previous
//
#include <hip/hip_runtime.h>
#include <stdint.h>

// Mamba forward, MI355X. Round 1:
//  - logits GEMM: XCD-swizzled (bijective, 400 col-tiles = 50/XCD), B read as
//    fp32 directly with in-reg bf16 convert (kills the 231MB convert pass)
//  - all bf16 GEMMs: global_load_lds width=16 staging (m97 structure)
//  - x_proj split-K x8, out_proj split-K x4 (+fused residual reduce)
//  - fused epilogues: softplus into dt-GEMM, y*silu(z)->bf16 into scanC
//  - single-pass shifted LSE (no max pass)

#define D_MODEL 768
#define N_LAYER 4
#define VOCAB 50257
#define VTILES 400          // 400*128 = 51200 >= VOCAB, 50 tiles per XCD
#define D_STATE 16
#define D_INNER 1536
#define DT_RANK 48
#define LSEQ 2048
#define TCHUNK 64
#define NCHUNK 32

typedef unsigned short u16;
typedef __attribute__((ext_vector_type(8))) short short8;
typedef __attribute__((ext_vector_type(8))) unsigned short ushort8;
typedef __attribute__((ext_vector_type(4))) float f32x4;

__device__ __forceinline__ u16 f2bf(float f) {
  unsigned int x = __float_as_uint(f);
  x += 0x7fffu + ((x >> 16) & 1u);   // RNE
  return (u16)(x >> 16);
}

__device__ __forceinline__ void gl16(const void* g, void* l) {
  __builtin_amdgcn_global_load_lds((const __attribute__((address_space(1))) void*)g,
                                   (__attribute__((address_space(3))) void*)l, 16, 0, 0);
}

// ---------------- weight conversion with zero padding ------------------------
__global__ void k_convert_pad(const float* __restrict__ src, u16* __restrict__ dst,
                              int N, int K, int Kpad, long total) {
  long i = (long)blockIdx.x * 256 + threadIdx.x;
  if (i >= total) return;
  int n = (int)(i / Kpad), k = (int)(i % Kpad);
  float v = (n < N && k < K) ? src[(long)n * K + k] : 0.0f;
  dst[i] = f2bf(v);
}

// ---------------- embedding gather (fp32) -----------------------------------
__global__ void k_embed(const int* __restrict__ idx, const float* __restrict__ emb,
                        float* __restrict__ x) {
  int i = blockIdx.x * 256 + threadIdx.x;
  int t = i / D_MODEL, c = i % D_MODEL;
  x[i] = emb[(long)idx[t] * D_MODEL + c];
}

// ---------------- rmsnorm -> bf16 -------------------------------------------
__global__ void k_rmsnorm_bf16(const float* __restrict__ x, const float* __restrict__ w,
                               u16* __restrict__ out) {
  int t = blockIdx.x, tid = threadIdx.x;
  __shared__ float red[256];
  const float* row = x + (long)t * D_MODEL;
  float s = 0.0f;
  for (int c = tid; c < D_MODEL; c += 256) { float v = row[c]; s += v * v; }
  red[tid] = s; __syncthreads();
  for (int o = 128; o > 0; o >>= 1) { if (tid < o) red[tid] += red[tid + o]; __syncthreads(); }
  float scale = rsqrtf(red[0] / (float)D_MODEL + 1e-5f);
  for (int c = tid; c < D_MODEL; c += 256) out[(long)t * D_MODEL + c] = f2bf(row[c] * scale * w[c]);
}

// ---------------- GEMM core (bf16 A,W via global_load_lds) -------------------
// C(M,N) fp32 = A(M,K) * W(N,K)^T.  EPI: 0 = plain store, 1 = softplus(acc+bias[col])
template<int EPI>
__global__ __launch_bounds__(256) void k_gemm(
    const u16* __restrict__ A, const u16* __restrict__ W, float* __restrict__ C,
    const float* __restrict__ bias, int N, int K, int lda, int ldb, int ldc) {
  __shared__ u16 lA[128 * 32];
  __shared__ u16 lB[128 * 32];
  const int tid = threadIdx.x, wid = tid >> 6, lane = tid & 63;
  const int brow = blockIdx.y * 128, bcol = blockIdx.x * 128;
  const int wm = (wid >> 1) * 64, wn = (wid & 1) * 64;
  const int fr = lane & 15, fq = lane >> 4, kh = fq * 8;
  const int srow = tid >> 2, scol = (tid & 3) * 8;
  const u16* ga0 = A + (size_t)(brow + srow) * lda + scol;
  const u16* ga1 = A + (size_t)(brow + srow + 64) * lda + scol;
  const u16* gb0 = W + (size_t)(bcol + srow) * ldb + scol;
  const u16* gb1 = W + (size_t)(bcol + srow + 64) * ldb + scol;
  u16* la0 = &lA[srow * 32 + scol];
  u16* la1 = &lA[(srow + 64) * 32 + scol];
  u16* lb0 = &lB[srow * 32 + scol];
  u16* lb1 = &lB[(srow + 64) * 32 + scol];

  f32x4 acc[4][4];
#pragma unroll
  for (int i = 0; i < 4; i++)
#pragma unroll
    for (int j = 0; j < 4; j++)
#pragma unroll
      for (int r = 0; r < 4; r++) acc[i][j][r] = 0.0f;

  for (int k0 = 0; k0 < K; k0 += 32) {
    gl16(ga0 + k0, la0); gl16(ga1 + k0, la1);
    gl16(gb0 + k0, lb0); gl16(gb1 + k0, lb1);
    __syncthreads();
    short8 af[4], bf[4];
#pragma unroll
    for (int i = 0; i < 4; i++) af[i] = *(const short8*)(&lA[(wm + i * 16 + fr) * 32 + kh]);
#pragma unroll
    for (int j = 0; j < 4; j++) bf[j] = *(const short8*)(&lB[(wn + j * 16 + fr) * 32 + kh]);
#pragma unroll
    for (int i = 0; i < 4; i++)
#pragma unroll
      for (int j = 0; j < 4; j++)
        acc[i][j] = __builtin_amdgcn_mfma_f32_16x16x32_bf16(af[i], bf[j], acc[i][j], 0, 0, 0);
    __syncthreads();
  }
#pragma unroll
  for (int i = 0; i < 4; i++)
#pragma unroll
    for (int j = 0; j < 4; j++) {
      int col = bcol + wn + j * 16 + fr;
      if (col < N) {
#pragma unroll
        for (int r = 0; r < 4; r++) {
          int row = brow + wm + i * 16 + fq * 4 + r;
          float v = acc[i][j][r];
          if (EPI == 1) {
            v += bias[col];
            v = (v > 20.0f) ? v : log1pf(__expf(v));
          }
          C[(size_t)row * ldc + col] = v;
        }
      }
    }
}

// ---------------- split-K partial GEMM (writes Cp[z][M][ldc]) ----------------
__global__ __launch_bounds__(256) void k_gemm_part(
    const u16* __restrict__ A, const u16* __restrict__ W, float* __restrict__ Cp,
    int N, int Ks, int lda, int ldb, int ldc) {
  __shared__ u16 lA[128 * 32];
  __shared__ u16 lB[128 * 32];
  const int tid = threadIdx.x, wid = tid >> 6, lane = tid & 63;
  const int brow = blockIdx.y * 128, bcol = blockIdx.x * 128;
  const int koff = blockIdx.z * Ks;
  const int wm = (wid >> 1) * 64, wn = (wid & 1) * 64;
  const int fr = lane & 15, fq = lane >> 4, kh = fq * 8;
  const int srow = tid >> 2, scol = (tid & 3) * 8;
  const u16* ga0 = A + (size_t)(brow + srow) * lda + scol;
  const u16* ga1 = A + (size_t)(brow + srow + 64) * lda + scol;
  const u16* gb0 = W + (size_t)(bcol + srow) * ldb + scol;
  const u16* gb1 = W + (size_t)(bcol + srow + 64) * ldb + scol;
  u16* la0 = &lA[srow * 32 + scol];
  u16* la1 = &lA[(srow + 64) * 32 + scol];
  u16* lb0 = &lB[srow * 32 + scol];
  u16* lb1 = &lB[(srow + 64) * 32 + scol];

  f32x4 acc[4][4];
#pragma unroll
  for (int i = 0; i < 4; i++)
#pragma unroll
    for (int j = 0; j < 4; j++)
#pragma unroll
      for (int r = 0; r < 4; r++) acc[i][j][r] = 0.0f;

  for (int k0 = koff; k0 < koff + Ks; k0 += 32) {
    gl16(ga0 + k0, la0); gl16(ga1 + k0, la1);
    gl16(gb0 + k0, lb0); gl16(gb1 + k0, lb1);
    __syncthreads();
    short8 af[4], bf[4];
#pragma unroll
    for (int i = 0; i < 4; i++) af[i] = *(const short8*)(&lA[(wm + i * 16 + fr) * 32 + kh]);
#pragma unroll
    for (int j = 0; j < 4; j++) bf[j] = *(const short8*)(&lB[(wn + j * 16 + fr) * 32 + kh]);
#pragma unroll
    for (int i = 0; i < 4; i++)
#pragma unroll
      for (int j = 0; j < 4; j++)
        acc[i][j] = __builtin_amdgcn_mfma_f32_16x16x32_bf16(af[i], bf[j], acc[i][j], 0, 0, 0);
    __syncthreads();
  }
  float* Cz = Cp + (size_t)blockIdx.z * LSEQ * ldc;
#pragma unroll
  for (int i = 0; i < 4; i++)
#pragma unroll
    for (int j = 0; j < 4; j++) {
      int col = bcol + wn + j * 16 + fr;
      if (col < N) {
#pragma unroll
        for (int r = 0; r < 4; r++) {
          int row = brow + wm + i * 16 + fq * 4 + r;
          Cz[(size_t)row * ldc + col] = acc[i][j][r];
        }
      }
    }
}

__global__ void k_red_xproj(const float* __restrict__ part, float* __restrict__ xdbl) {
  int i = blockIdx.x * 256 + threadIdx.x;   // LSEQ*80
  float s = 0.0f;
#pragma unroll
  for (int p = 0; p < 8; p++) s += part[(size_t)p * LSEQ * 80 + i];
  xdbl[i] = s;
}

__global__ void k_red_outproj(const float* __restrict__ part, float* __restrict__ x) {
  int i = blockIdx.x * 256 + threadIdx.x;   // LSEQ*D_MODEL
  float s = 0.0f;
#pragma unroll
  for (int p = 0; p < 4; p++) s += part[(size_t)p * LSEQ * D_MODEL + i];
  x[i] += s;
}

// ---------------- logits GEMM: A bf16 (gload_lds), B fp32 emb (reg-staged) ---
// XCD-bijective swizzle: 400 col-tiles, 50 per XCD, 16 row-tiles walked
// consecutively within each col-tile.
__global__ __launch_bounds__(256) void k_gemm_logits(
    const u16* __restrict__ A, const float* __restrict__ Bf, float* __restrict__ C) {
  __shared__ u16 lA[128 * 32];
  __shared__ u16 lB[128 * 32];
  const int b = blockIdx.x;
  const int xcd = b & 7, slot = b >> 3;
  const int ct = xcd * 50 + (slot >> 4), rt = slot & 15;
  const int brow = rt * 128, bcol = ct * 128;
  const int tid = threadIdx.x, wid = tid >> 6, lane = tid & 63;
  const int wm = (wid >> 1) * 64, wn = (wid & 1) * 64;
  const int fr = lane & 15, fq = lane >> 4, kh = fq * 8;
  const int srow = tid >> 2, scol = (tid & 3) * 8;
  const int br2 = tid >> 3, bc4 = (tid & 7) * 4;

  f32x4 acc[4][4];
#pragma unroll
  for (int i = 0; i < 4; i++)
#pragma unroll
    for (int j = 0; j < 4; j++)
#pragma unroll
      for (int r = 0; r < 4; r++) acc[i][j][r] = 0.0f;

  for (int k0 = 0; k0 < D_MODEL; k0 += 32) {
    gl16(A + (size_t)(brow + srow) * D_MODEL + k0 + scol, &lA[srow * 32 + scol]);
    gl16(A + (size_t)(brow + srow + 64) * D_MODEL + k0 + scol, &lA[(srow + 64) * 32 + scol]);
#pragma unroll
    for (int rnd = 0; rnd < 4; rnd++) {
      int r = br2 + rnd * 32;
      int gr = bcol + r;
      float4 v = make_float4(0.f, 0.f, 0.f, 0.f);
      if (gr < VOCAB) v = *(const float4*)(Bf + (size_t)gr * D_MODEL + k0 + bc4);
      ushort4 h;
      h.x = f2bf(v.x); h.y = f2bf(v.y); h.z = f2bf(v.z); h.w = f2bf(v.w);
      *(ushort4*)(&lB[r * 32 + bc4]) = h;
    }
    __syncthreads();
    short8 af[4], bf[4];
#pragma unroll
    for (int i = 0; i < 4; i++) af[i] = *(const short8*)(&lA[(wm + i * 16 + fr) * 32 + kh]);
#pragma unroll
    for (int j = 0; j < 4; j++) bf[j] = *(const short8*)(&lB[(wn + j * 16 + fr) * 32 + kh]);
#pragma unroll
    for (int i = 0; i < 4; i++)
#pragma unroll
      for (int j = 0; j < 4; j++)
        acc[i][j] = __builtin_amdgcn_mfma_f32_16x16x32_bf16(af[i], bf[j], acc[i][j], 0, 0, 0);
    __syncthreads();
  }
#pragma unroll
  for (int i = 0; i < 4; i++)
#pragma unroll
    for (int j = 0; j < 4; j++) {
      int col = bcol + wn + j * 16 + fr;
      if (col < VOCAB) {
#pragma unroll
        for (int r = 0; r < 4; r++) {
          int row = brow + wm + i * 16 + fq * 4 + r;
          C[(size_t)row * VOCAB + col] = acc[i][j][r];
        }
      }
    }
}

// ---------------- causal conv1d (K=4) + silu --------------------------------
__global__ void k_conv_silu(const float* __restrict__ xz, const float* __restrict__ cw,
                            const float* __restrict__ cb, float* __restrict__ xif,
                            u16* __restrict__ xib) {
  int i = blockIdx.x * 256 + threadIdx.x;
  int t = i / D_INNER, d = i % D_INNER;
  float acc = cb[d];
#pragma unroll
  for (int k = 0; k < 4; k++) {
    int tt = t - 3 + k;
    if (tt >= 0) acc += xz[(long)tt * (2 * D_INNER) + d] * cw[d * 4 + k];
  }
  float s = acc / (1.0f + __expf(-acc));
  xif[i] = s;
  xib[i] = f2bf(s);
}

// ---------------- dt slice of xdbl -> bf16 padded to 64 ---------------------
__global__ void k_dtpad(const float* __restrict__ xdbl, u16* __restrict__ dtp) {
  int i = blockIdx.x * 256 + threadIdx.x;
  int t = i >> 6, k = i & 63;
  dtp[i] = (k < DT_RANK) ? f2bf(xdbl[(long)t * 80 + k]) : (u16)0;
}

// ---------------- selective scan: 3-phase chunked ----------------------------
__global__ void k_scanA(const float* __restrict__ dt, const float* __restrict__ xi,
                        const float* __restrict__ xdbl, const float* __restrict__ a_log,
                        float* __restrict__ aprod, float* __restrict__ hend) {
  int d = blockIdx.x * 256 + threadIdx.x;
  int c = blockIdx.y;
  float A[16], ap[16], h[16];
#pragma unroll
  for (int s = 0; s < 16; s++) { A[s] = -__expf(a_log[d * 16 + s]); ap[s] = 1.0f; h[s] = 0.0f; }
  int t0 = c * TCHUNK;
  for (int t = t0; t < t0 + TCHUNK; t++) {
    float dtv = dt[(long)t * D_INNER + d], xv = xi[(long)t * D_INNER + d];
    float dx = dtv * xv;
    const float* Bp = xdbl + (long)t * 80 + DT_RANK;
#pragma unroll
    for (int s = 0; s < 16; s++) {
      float a = __expf(dtv * A[s]);
      h[s] = a * h[s] + dx * Bp[s];
      ap[s] *= a;
    }
  }
  long base = ((long)c * D_INNER + d) * 16;
#pragma unroll
  for (int s = 0; s < 16; s++) { aprod[base + s] = ap[s]; hend[base + s] = h[s]; }
}

__global__ void k_scanB(const float* __restrict__ aprod, const float* __restrict__ hend,
                        float* __restrict__ hinit) {
  int i = blockIdx.x * 256 + threadIdx.x;
  float h = 0.0f;
  for (int c = 0; c < NCHUNK; c++) {
    long idx = (long)c * D_INNER * 16 + i;
    hinit[idx] = h;
    h = aprod[idx] * h + hend[idx];
  }
}

// phase C fused with y*silu(z) -> bf16
__global__ void k_scanC(const float* __restrict__ dt, const float* __restrict__ xi,
                        const float* __restrict__ xdbl, const float* __restrict__ a_log,
                        const float* __restrict__ hinit, const float* __restrict__ Dp,
                        const float* __restrict__ xz, u16* __restrict__ yb) {
  int d = blockIdx.x * 256 + threadIdx.x;
  int c = blockIdx.y;
  float A[16], h[16];
  long hb = (long)c * D_INNER * 16 + (long)d * 16;
#pragma unroll
  for (int s = 0; s < 16; s++) { A[s] = -__expf(a_log[d * 16 + s]); h[s] = hinit[hb + s]; }
  float Dv = Dp[d];
  int t0 = c * TCHUNK;
  for (int t = t0; t < t0 + TCHUNK; t++) {
    float dtv = dt[(long)t * D_INNER + d], xv = xi[(long)t * D_INNER + d];
    float dx = dtv * xv;
    const float* Bp = xdbl + (long)t * 80 + DT_RANK;
    const float* Cp = Bp + D_STATE;
    float o = xv * Dv;
#pragma unroll
    for (int s = 0; s < 16; s++) {
      float a = __expf(dtv * A[s]);
      h[s] = a * h[s] + dx * Bp[s];
      o += h[s] * Cp[s];
    }
    float z = xz[(long)t * (2 * D_INNER) + D_INNER + d];
    yb[(long)t * D_INNER + d] = f2bf(o * (z / (1.0f + __expf(-z))));
  }
}

// ---------------- single-pass shifted LSE + nll ------------------------------
__global__ void k_row_lse(const float* __restrict__ logits, const int* __restrict__ tgt,
                          float* __restrict__ nll, float* __restrict__ msk) {
  int t = blockIdx.x, tid = threadIdx.x;
  __shared__ float red[256];
  const float* row = logits + (size_t)t * VOCAB;
  float s = 0.0f;
  for (int c = tid; c < VOCAB; c += 256) s += __expf(row[c] - 20.0f);
  red[tid] = s; __syncthreads();
  for (int o = 128; o > 0; o >>= 1) { if (tid < o) red[tid] += red[tid + o]; __syncthreads(); }
  if (tid == 0) {
    float lse = 20.0f + __logf(red[0]);
    int tg = tgt[t];
    float mk = tg >= 0 ? 1.0f : 0.0f;
    int tc = tg < 0 ? 0 : (tg > VOCAB - 1 ? VOCAB - 1 : tg);
    nll[t] = (lse - row[tc]) * mk;
    msk[t] = mk;
  }
}

__global__ void k_loss(const float* __restrict__ nll, const float* __restrict__ msk,
                       float* __restrict__ out) {
  int tid = threadIdx.x;
  __shared__ float r1[256], r2[256];
  float a = 0.0f, b = 0.0f;
  for (int i = tid; i < LSEQ; i += 256) { a += nll[i]; b += msk[i]; }
  r1[tid] = a; r2[tid] = b; __syncthreads();
  for (int o = 128; o > 0; o >>= 1) {
    if (tid < o) { r1[tid] += r1[tid + o]; r2[tid] += r2[tid + o]; }
    __syncthreads();
  }
  if (tid == 0) out[0] = r1[0] / fmaxf(r2[0], 1.0f);
}

// =============================================================================
extern "C" void kernel_launch(void* const* d_in, const int* in_sizes, int n_in,
                              void* d_out, int out_size, void* d_ws, size_t ws_size,
                              hipStream_t stream) {
  const int*   idx    = (const int*)d_in[0];
  const int*   tgt    = (const int*)d_in[1];
  const float* emb    = (const float*)d_in[2];
  const float* norm_w = (const float*)d_in[3];
  const float* in_w   = (const float*)d_in[4];
  const float* conv_w = (const float*)d_in[5];
  const float* conv_b = (const float*)d_in[6];
  const float* xp_w   = (const float*)d_in[7];
  const float* dt_w   = (const float*)d_in[8];
  const float* dt_b   = (const float*)d_in[9];
  const float* a_log  = (const float*)d_in[10];
  const float* d_par  = (const float*)d_in[11];
  const float* out_w  = (const float*)d_in[12];
  const float* normf  = (const float*)d_in[13];

  float* logits = (float*)d_out;
  float* loss   = logits + (size_t)LSEQ * VOCAB;

  char* base = (char*)d_ws;
  size_t off = 0;
  auto alloc = [&](size_t bytes) -> char* {
    char* r = base + off;
    off = (off + bytes + 255) & ~(size_t)255;
    return r;
  };
  float* x    = (float*)alloc((size_t)LSEQ * D_MODEL * 4);
  u16*   xnb  = (u16*)  alloc((size_t)LSEQ * D_MODEL * 2);
  float* xz   = (float*)alloc((size_t)LSEQ * 2 * D_INNER * 4);
  float* xif  = (float*)alloc((size_t)LSEQ * D_INNER * 4);
  u16*   xib  = (u16*)  alloc((size_t)LSEQ * D_INNER * 2);
  u16*   w1   = (u16*)  alloc((size_t)2 * D_INNER * D_MODEL * 2);
  u16*   w2   = (u16*)  alloc((size_t)128 * D_INNER * 2);
  u16*   w3   = (u16*)  alloc((size_t)D_INNER * 64 * 2);
  u16*   w4   = (u16*)  alloc((size_t)D_MODEL * D_INNER * 2);
  float* xdbl = (float*)alloc((size_t)LSEQ * 80 * 4);
  u16*   dtp  = (u16*)  alloc((size_t)LSEQ * 64 * 2);
  float* dtl  = (float*)alloc((size_t)LSEQ * D_INNER * 4);
  u16*   yb   = (u16*)  alloc((size_t)LSEQ * D_INNER * 2);
  float* pxp  = (float*)alloc((size_t)8 * LSEQ * 80 * 4);
  float* pop  = (float*)alloc((size_t)4 * LSEQ * D_MODEL * 4);
  float* apr  = (float*)alloc((size_t)NCHUNK * D_INNER * 16 * 4);
  float* hen  = (float*)alloc((size_t)NCHUNK * D_INNER * 16 * 4);
  float* hin  = (float*)alloc((size_t)NCHUNK * D_INNER * 16 * 4);
  float* nll  = (float*)alloc((size_t)LSEQ * 4);
  float* msk  = (float*)alloc((size_t)LSEQ * 4);
  (void)ws_size; (void)in_sizes; (void)n_in; (void)out_size;

  k_embed<<<(LSEQ * D_MODEL) / 256, 256, 0, stream>>>(idx, emb, x);

  for (int l = 0; l < N_LAYER; l++) {
    k_rmsnorm_bf16<<<LSEQ, 256, 0, stream>>>(x, norm_w + l * D_MODEL, xnb);

    { long tot = (long)2 * D_INNER * D_MODEL;
      k_convert_pad<<<(unsigned)((tot + 255) / 256), 256, 0, stream>>>(
          in_w + (long)l * 2 * D_INNER * D_MODEL, w1, 2 * D_INNER, D_MODEL, D_MODEL, tot); }
    k_gemm<0><<<dim3(2 * D_INNER / 128, LSEQ / 128), 256, 0, stream>>>(
        xnb, w1, xz, nullptr, 2 * D_INNER, D_MODEL, D_MODEL, D_MODEL, 2 * D_INNER);

    k_conv_silu<<<(LSEQ * D_INNER) / 256, 256, 0, stream>>>(
        xz, conv_w + (long)l * D_INNER * 4, conv_b + l * D_INNER, xif, xib);

    { long tot = (long)128 * D_INNER;
      k_convert_pad<<<(unsigned)((tot + 255) / 256), 256, 0, stream>>>(
          xp_w + (long)l * 80 * D_INNER, w2, 80, D_INNER, D_INNER, tot); }
    k_gemm_part<<<dim3(1, LSEQ / 128, 8), 256, 0, stream>>>(
        xib, w2, pxp, 80, D_INNER / 8, D_INNER, D_INNER, 80);
    k_red_xproj<<<(LSEQ * 80) / 256, 256, 0, stream>>>(pxp, xdbl);

    k_dtpad<<<(LSEQ * 64) / 256, 256, 0, stream>>>(xdbl, dtp);
    { long tot = (long)D_INNER * 64;
      k_convert_pad<<<(unsigned)((tot + 255) / 256), 256, 0, stream>>>(
          dt_w + (long)l * D_INNER * DT_RANK, w3, D_INNER, DT_RANK, 64, tot); }
    k_gemm<1><<<dim3(D_INNER / 128, LSEQ / 128), 256, 0, stream>>>(
        dtp, w3, dtl, dt_b + l * D_INNER, D_INNER, 64, 64, 64, D_INNER);

    const float* al = a_log + (long)l * D_INNER * D_STATE;
    k_scanA<<<dim3(D_INNER / 256, NCHUNK), 256, 0, stream>>>(dtl, xif, xdbl, al, apr, hen);
    k_scanB<<<(D_INNER * 16) / 256, 256, 0, stream>>>(apr, hen, hin);
    k_scanC<<<dim3(D_INNER / 256, NCHUNK), 256, 0, stream>>>(
        dtl, xif, xdbl, al, hin, d_par + l * D_INNER, xz, yb);

    { long tot = (long)D_MODEL * D_INNER;
      k_convert_pad<<<(unsigned)((tot + 255) / 256), 256, 0, stream>>>(
          out_w + (long)l * D_MODEL * D_INNER, w4, D_MODEL, D_INNER, D_INNER, tot); }
    k_gemm_part<<<dim3(D_MODEL / 128, LSEQ / 128, 4), 256, 0, stream>>>(
        yb, w4, pop, D_MODEL, D_INNER / 4, D_INNER, D_INNER, D_MODEL);
    k_red_outproj<<<(LSEQ * D_MODEL) / 256, 256, 0, stream>>>(pop, x);
  }

  k_rmsnorm_bf16<<<LSEQ, 256, 0, stream>>>(x, normf, xnb);
  k_gemm_logits<<<VTILES * (LSEQ / 128), 256, 0, stream>>>(xnb, emb, logits);

  k_row_lse<<<LSEQ, 256, 0, stream>>>(logits, tgt, nll, msk);
  k_loss<<<1, 256, 0, stream>>>(nll, msk, loss);
}

// Round 3
// 1388.041 us; speedup vs baseline: 1.1939x; 1.1144x over previous
//
#include <hip/hip_runtime.h>
#include <stdint.h>

// Mamba forward, MI355X. Round 3:
//  - logits GEMM: all-bf16, 2-phase double-buffered global_load_lds, XCD
//    bijective swizzle, FUSED row-wise exp-sum partials (kills k_row_lse)
//  - all GEMMs: 2-phase dbuf + XCD swizzle
//  - single upfront convert kernel (emb + all weights, zero-padded)
//  - fusions: embed+rms0; outproj-reduce+residual+rmsnorm; xproj-reduce+dtpad
//  - xz stored bf16; scans read bf16 xi

#define D_MODEL 768
#define N_LAYER 4
#define VOCAB 50257
#define D_STATE 16
#define D_INNER 1536
#define DT_RANK 48
#define LSEQ 2048
#define TCHUNK 64
#define NCHUNK 32

// padded bf16 weight arena layout
#define EMB_E 39321600L            // 51200*768
#define W1E 2359296L               // 3072*768
#define W2E 196608L                // 128*1536 (N 80->128)
#define W3E 98304L                 // 1536*64  (K 48->64)
#define W4E 1179648L               // 768*1536
#define PERL (W1E + W2E + W3E + W4E)
#define TOTCVT (EMB_E + 4 * PERL)  // 54,657,024

typedef unsigned short u16;
typedef __attribute__((ext_vector_type(8))) short short8;
typedef __attribute__((ext_vector_type(4))) float f32x4;

__device__ __forceinline__ u16 f2bf(float f) {
  unsigned int x = __float_as_uint(f);
  x += 0x7fffu + ((x >> 16) & 1u);   // RNE
  return (u16)(x >> 16);
}
__device__ __forceinline__ float bf2f(u16 v) {
  return __uint_as_float(((unsigned int)v) << 16);
}
__device__ __forceinline__ void gl16(const void* g, void* l) {
  __builtin_amdgcn_global_load_lds((const __attribute__((address_space(1))) void*)g,
                                   (__attribute__((address_space(3))) void*)l, 16, 0, 0);
}

// ---------------- upfront convert: emb + all layer weights -> bf16 arena -----
__global__ void k_convert_all(const float* __restrict__ emb, const float* __restrict__ in_w,
                              const float* __restrict__ xp_w, const float* __restrict__ dt_w,
                              const float* __restrict__ out_w, u16* __restrict__ dst) {
  long i = (long)blockIdx.x * 256 + threadIdx.x;
  float v;
  if (i < EMB_E) {
    long n = i / D_MODEL, k = i % D_MODEL;
    v = (n < VOCAB) ? emb[n * D_MODEL + k] : 0.0f;
  } else {
    long j = i - EMB_E;
    int l = (int)(j / PERL);
    long m = j % PERL;
    if (m < W1E) {
      v = in_w[(long)l * W1E + m];
    } else if (m < W1E + W2E) {
      long mm = m - W1E;
      long n = mm / D_INNER, k = mm % D_INNER;
      v = (n < 80) ? xp_w[(long)l * 80 * D_INNER + n * D_INNER + k] : 0.0f;
    } else if (m < W1E + W2E + W3E) {
      long mm = m - (W1E + W2E);
      long n = mm / 64, k = mm % 64;
      v = (k < DT_RANK) ? dt_w[(long)l * D_INNER * DT_RANK + n * DT_RANK + k] : 0.0f;
    } else {
      long mm = m - (W1E + W2E + W3E);
      v = out_w[(long)l * W4E + mm];
    }
  }
  dst[i] = f2bf(v);
}

// ---------------- embed + rmsnorm(layer0) ------------------------------------
__global__ void k_embed_rms(const int* __restrict__ idx, const float* __restrict__ emb,
                            const float* __restrict__ w, float* __restrict__ x,
                            u16* __restrict__ xnb) {
  int t = blockIdx.x, tid = threadIdx.x;
  __shared__ float red[256];
  const float* src = emb + (long)idx[t] * D_MODEL;
  float g[3];
  float s = 0.0f;
#pragma unroll
  for (int q = 0; q < 3; q++) {
    g[q] = src[tid + q * 256];
    s += g[q] * g[q];
  }
  red[tid] = s; __syncthreads();
  for (int o = 128; o > 0; o >>= 1) { if (tid < o) red[tid] += red[tid + o]; __syncthreads(); }
  float scale = rsqrtf(red[0] / (float)D_MODEL + 1e-5f);
#pragma unroll
  for (int q = 0; q < 3; q++) {
    int c = tid + q * 256;
    x[(long)t * D_MODEL + c] = g[q];
    xnb[(long)t * D_MODEL + c] = f2bf(g[q] * scale * w[c]);
  }
}

// ---------------- reduce out_proj partials + residual + rmsnorm --------------
__global__ void k_rms_red(const float* __restrict__ part, const float* __restrict__ w,
                          float* __restrict__ x, u16* __restrict__ xnb) {
  int t = blockIdx.x, tid = threadIdx.x;
  __shared__ float red[256];
  float g[3];
  float s = 0.0f;
#pragma unroll
  for (int q = 0; q < 3; q++) {
    int c = tid + q * 256;
    long off = (long)t * D_MODEL + c;
    float v = x[off];
#pragma unroll
    for (int p = 0; p < 4; p++) v += part[(size_t)p * LSEQ * D_MODEL + off];
    g[q] = v;
    s += v * v;
  }
  red[tid] = s; __syncthreads();
  for (int o = 128; o > 0; o >>= 1) { if (tid < o) red[tid] += red[tid + o]; __syncthreads(); }
  float scale = rsqrtf(red[0] / (float)D_MODEL + 1e-5f);
#pragma unroll
  for (int q = 0; q < 3; q++) {
    int c = tid + q * 256;
    x[(long)t * D_MODEL + c] = g[q];
    xnb[(long)t * D_MODEL + c] = f2bf(g[q] * scale * w[c]);
  }
}

// ---------------- 2-phase dbuf GEMM: C = A(M,K) * W(N,K)^T -------------------
// EPI: 1 = softplus(acc+bias[col]) -> fp32, 2 = bf16 store
template<int EPI>
__global__ __launch_bounds__(256) void k_gemm2(
    const u16* __restrict__ A, const u16* __restrict__ W, void* __restrict__ Cv,
    const float* __restrict__ bias, int N, int K, int lda, int ldb, int ldc) {
  __shared__ u16 lA[2][128 * 32];
  __shared__ u16 lB[2][128 * 32];
  // XCD-bijective swizzle, col-major walk (weight-tile reuse within XCD)
  const int gx = gridDim.x, gy = gridDim.y;
  int id = blockIdx.x + gx * blockIdx.y;
  int q8 = (gx * gy) >> 3;
  int v = (id & 7) * q8 + (id >> 3);
  const int bx = v / gy, by = v % gy;
  const int brow = by * 128, bcol = bx * 128;
  const int tid = threadIdx.x, wid = tid >> 6, lane = tid & 63;
  const int wm = (wid >> 1) * 64, wn = (wid & 1) * 64;
  const int fr = lane & 15, fq = lane >> 4, kh = fq * 8;
  const int srow = tid >> 2, scol = (tid & 3) * 8;
  const u16* ga0 = A + (size_t)(brow + srow) * lda + scol;
  const u16* ga1 = A + (size_t)(brow + srow + 64) * lda + scol;
  const u16* gb0 = W + (size_t)(bcol + srow) * ldb + scol;
  const u16* gb1 = W + (size_t)(bcol + srow + 64) * ldb + scol;
  const int lo = srow * 32 + scol;

  f32x4 acc[4][4];
#pragma unroll
  for (int i = 0; i < 4; i++)
#pragma unroll
    for (int j = 0; j < 4; j++)
#pragma unroll
      for (int r = 0; r < 4; r++) acc[i][j][r] = 0.0f;

  auto STAGE = [&](int k0, int b) {
    gl16(ga0 + k0, &lA[b][lo]);
    gl16(ga1 + k0, &lA[b][lo + 64 * 32]);
    gl16(gb0 + k0, &lB[b][lo]);
    gl16(gb1 + k0, &lB[b][lo + 64 * 32]);
  };

  const int nt = K / 32;
  STAGE(0, 0);
  __syncthreads();
  int cur = 0;
  for (int t = 0; t < nt; t++) {
    if (t + 1 < nt) STAGE((t + 1) * 32, cur ^ 1);
    short8 af[4], bfr[4];
#pragma unroll
    for (int i = 0; i < 4; i++) af[i] = *(const short8*)(&lA[cur][(wm + i * 16 + fr) * 32 + kh]);
#pragma unroll
    for (int j = 0; j < 4; j++) bfr[j] = *(const short8*)(&lB[cur][(wn + j * 16 + fr) * 32 + kh]);
#pragma unroll
    for (int i = 0; i < 4; i++)
#pragma unroll
      for (int j = 0; j < 4; j++)
        acc[i][j] = __builtin_amdgcn_mfma_f32_16x16x32_bf16(af[i], bfr[j], acc[i][j], 0, 0, 0);
    __syncthreads();
    cur ^= 1;
  }
#pragma unroll
  for (int i = 0; i < 4; i++)
#pragma unroll
    for (int j = 0; j < 4; j++) {
      int col = bcol + wn + j * 16 + fr;
      if (col < N) {
#pragma unroll
        for (int r = 0; r < 4; r++) {
          int row = brow + wm + i * 16 + fq * 4 + r;
          float val = acc[i][j][r];
          if (EPI == 1) {
            val += bias[col];
            val = (val > 20.0f) ? val : log1pf(__expf(val));
            ((float*)Cv)[(size_t)row * ldc + col] = val;
          } else {
            ((u16*)Cv)[(size_t)row * ldc + col] = f2bf(val);
          }
        }
      }
    }
}

// ---------------- split-K partial GEMM (2-phase dbuf) ------------------------
__global__ __launch_bounds__(256) void k_gemm_part(
    const u16* __restrict__ A, const u16* __restrict__ W, float* __restrict__ Cp,
    int N, int Ks, int lda, int ldb, int ldc) {
  __shared__ u16 lA[2][128 * 32];
  __shared__ u16 lB[2][128 * 32];
  const int gx = gridDim.x, gy = gridDim.y;
  int id = blockIdx.x + gx * blockIdx.y;
  int q8 = (gx * gy) >> 3;
  int v = (id & 7) * q8 + (id >> 3);
  const int bx = v / gy, by = v % gy;
  const int brow = by * 128, bcol = bx * 128;
  const int koff = blockIdx.z * Ks;
  const int tid = threadIdx.x, wid = tid >> 6, lane = tid & 63;
  const int wm = (wid >> 1) * 64, wn = (wid & 1) * 64;
  const int fr = lane & 15, fq = lane >> 4, kh = fq * 8;
  const int srow = tid >> 2, scol = (tid & 3) * 8;
  const u16* ga0 = A + (size_t)(brow + srow) * lda + koff + scol;
  const u16* ga1 = A + (size_t)(brow + srow + 64) * lda + koff + scol;
  const u16* gb0 = W + (size_t)(bcol + srow) * ldb + koff + scol;
  const u16* gb1 = W + (size_t)(bcol + srow + 64) * ldb + koff + scol;
  const int lo = srow * 32 + scol;

  f32x4 acc[4][4];
#pragma unroll
  for (int i = 0; i < 4; i++)
#pragma unroll
    for (int j = 0; j < 4; j++)
#pragma unroll
      for (int r = 0; r < 4; r++) acc[i][j][r] = 0.0f;

  auto STAGE = [&](int k0, int b) {
    gl16(ga0 + k0, &lA[b][lo]);
    gl16(ga1 + k0, &lA[b][lo + 64 * 32]);
    gl16(gb0 + k0, &lB[b][lo]);
    gl16(gb1 + k0, &lB[b][lo + 64 * 32]);
  };

  const int nt = Ks / 32;
  STAGE(0, 0);
  __syncthreads();
  int cur = 0;
  for (int t = 0; t < nt; t++) {
    if (t + 1 < nt) STAGE((t + 1) * 32, cur ^ 1);
    short8 af[4], bfr[4];
#pragma unroll
    for (int i = 0; i < 4; i++) af[i] = *(const short8*)(&lA[cur][(wm + i * 16 + fr) * 32 + kh]);
#pragma unroll
    for (int j = 0; j < 4; j++) bfr[j] = *(const short8*)(&lB[cur][(wn + j * 16 + fr) * 32 + kh]);
#pragma unroll
    for (int i = 0; i < 4; i++)
#pragma unroll
      for (int j = 0; j < 4; j++)
        acc[i][j] = __builtin_amdgcn_mfma_f32_16x16x32_bf16(af[i], bfr[j], acc[i][j], 0, 0, 0);
    __syncthreads();
    cur ^= 1;
  }
  float* Cz = Cp + (size_t)blockIdx.z * LSEQ * ldc;
#pragma unroll
  for (int i = 0; i < 4; i++)
#pragma unroll
    for (int j = 0; j < 4; j++) {
      int col = bcol + wn + j * 16 + fr;
      if (col < N) {
#pragma unroll
        for (int r = 0; r < 4; r++) {
          int row = brow + wm + i * 16 + fq * 4 + r;
          Cz[(size_t)row * ldc + col] = acc[i][j][r];
        }
      }
    }
}

// ---------------- logits GEMM + fused exp-sum partials -----------------------
// 400 col-tiles (50/XCD), 16 row-tiles; part[pcol][row], pcol = ct*2 + wn-half
__global__ __launch_bounds__(256) void k_gemm_logits(
    const u16* __restrict__ A, const u16* __restrict__ W, float* __restrict__ C,
    float* __restrict__ part) {
  __shared__ u16 lA[2][128 * 32];
  __shared__ u16 lB[2][128 * 32];
  const int b = blockIdx.x;
  const int xcd = b & 7, slot = b >> 3;
  const int ct = xcd * 50 + (slot >> 4), rt = slot & 15;
  const int brow = rt * 128, bcol = ct * 128;
  const int tid = threadIdx.x, wid = tid >> 6, lane = tid & 63;
  const int wm = (wid >> 1) * 64, wn = (wid & 1) * 64;
  const int fr = lane & 15, fq = lane >> 4, kh = fq * 8;
  const int srow = tid >> 2, scol = (tid & 3) * 8;
  const u16* ga0 = A + (size_t)(brow + srow) * D_MODEL + scol;
  const u16* ga1 = A + (size_t)(brow + srow + 64) * D_MODEL + scol;
  const u16* gb0 = W + (size_t)(bcol + srow) * D_MODEL + scol;
  const u16* gb1 = W + (size_t)(bcol + srow + 64) * D_MODEL + scol;
  const int lo = srow * 32 + scol;

  f32x4 acc[4][4];
#pragma unroll
  for (int i = 0; i < 4; i++)
#pragma unroll
    for (int j = 0; j < 4; j++)
#pragma unroll
      for (int r = 0; r < 4; r++) acc[i][j][r] = 0.0f;

  auto STAGE = [&](int k0, int bb) {
    gl16(ga0 + k0, &lA[bb][lo]);
    gl16(ga1 + k0, &lA[bb][lo + 64 * 32]);
    gl16(gb0 + k0, &lB[bb][lo]);
    gl16(gb1 + k0, &lB[bb][lo + 64 * 32]);
  };

  STAGE(0, 0);
  __syncthreads();
  int cur = 0;
  for (int t = 0; t < D_MODEL / 32; t++) {
    if (t + 1 < D_MODEL / 32) STAGE((t + 1) * 32, cur ^ 1);
    short8 af[4], bfr[4];
#pragma unroll
    for (int i = 0; i < 4; i++) af[i] = *(const short8*)(&lA[cur][(wm + i * 16 + fr) * 32 + kh]);
#pragma unroll
    for (int j = 0; j < 4; j++) bfr[j] = *(const short8*)(&lB[cur][(wn + j * 16 + fr) * 32 + kh]);
#pragma unroll
    for (int i = 0; i < 4; i++)
#pragma unroll
      for (int j = 0; j < 4; j++)
        acc[i][j] = __builtin_amdgcn_mfma_f32_16x16x32_bf16(af[i], bfr[j], acc[i][j], 0, 0, 0);
    __syncthreads();
    cur ^= 1;
  }
  float rs[16];
#pragma unroll
  for (int q = 0; q < 16; q++) rs[q] = 0.0f;
#pragma unroll
  for (int i = 0; i < 4; i++)
#pragma unroll
    for (int j = 0; j < 4; j++) {
      int col = bcol + wn + j * 16 + fr;
      if (col < VOCAB) {
#pragma unroll
        for (int r = 0; r < 4; r++) {
          int row = brow + wm + i * 16 + fq * 4 + r;
          float val = acc[i][j][r];
          C[(size_t)row * VOCAB + col] = val;
          rs[i * 4 + r] += __expf(val - 20.0f);
        }
      }
    }
#pragma unroll
  for (int q = 0; q < 16; q++) {
    float s = rs[q];
    s += __shfl_xor(s, 1); s += __shfl_xor(s, 2);
    s += __shfl_xor(s, 4); s += __shfl_xor(s, 8);
    rs[q] = s;
  }
  if (fr == 0) {
    int pc = ct * 2 + (wn >> 6);
#pragma unroll
    for (int i = 0; i < 4; i++)
#pragma unroll
      for (int r = 0; r < 4; r++) {
        int row = brow + wm + i * 16 + fq * 4 + r;
        part[(size_t)pc * LSEQ + row] = rs[i * 4 + r];
      }
  }
}

// ---------------- causal conv1d (K=4) + silu -> bf16 -------------------------
__global__ void k_conv_silu(const u16* __restrict__ xzb, const float* __restrict__ cw,
                            const float* __restrict__ cb, u16* __restrict__ xib) {
  int i = blockIdx.x * 256 + threadIdx.x;
  int t = i / D_INNER, d = i % D_INNER;
  float acc = cb[d];
#pragma unroll
  for (int k = 0; k < 4; k++) {
    int tt = t - 3 + k;
    if (tt >= 0) acc += bf2f(xzb[(long)tt * (2 * D_INNER) + d]) * cw[d * 4 + k];
  }
  float s = acc / (1.0f + __expf(-acc));
  xib[i] = f2bf(s);
}

// ---------------- reduce x_proj partials -> xdbl + dt-pad bf16 ---------------
__global__ void k_red_xd(const float* __restrict__ pxp, float* __restrict__ xdbl,
                         u16* __restrict__ dtp) {
  int i = blockIdx.x * 256 + threadIdx.x;   // LSEQ*128
  int t = i >> 7, k = i & 127;
  if (k < 80) {
    float s = 0.0f;
#pragma unroll
    for (int p = 0; p < 8; p++) s += pxp[(size_t)p * LSEQ * 80 + (long)t * 80 + k];
    xdbl[(long)t * 80 + k] = s;
    if (k < DT_RANK) dtp[(long)t * 64 + k] = f2bf(s);
    else if (k < 64) dtp[(long)t * 64 + k] = 0;
  }
}

// ---------------- selective scan: 3-phase chunked ----------------------------
__global__ void k_scanA(const float* __restrict__ dt, const u16* __restrict__ xi,
                        const float* __restrict__ xdbl, const float* __restrict__ a_log,
                        float* __restrict__ aprod, float* __restrict__ hend) {
  int d = blockIdx.x * 256 + threadIdx.x;
  int c = blockIdx.y;
  float A[16], ap[16], h[16];
#pragma unroll
  for (int s = 0; s < 16; s++) { A[s] = -__expf(a_log[d * 16 + s]); ap[s] = 1.0f; h[s] = 0.0f; }
  int t0 = c * TCHUNK;
  for (int t = t0; t < t0 + TCHUNK; t++) {
    float dtv = dt[(long)t * D_INNER + d], xv = bf2f(xi[(long)t * D_INNER + d]);
    float dx = dtv * xv;
    const float* Bp = xdbl + (long)t * 80 + DT_RANK;
#pragma unroll
    for (int s = 0; s < 16; s++) {
      float a = __expf(dtv * A[s]);
      h[s] = a * h[s] + dx * Bp[s];
      ap[s] *= a;
    }
  }
  long base = ((long)c * D_INNER + d) * 16;
#pragma unroll
  for (int s = 0; s < 16; s++) { aprod[base + s] = ap[s]; hend[base + s] = h[s]; }
}

__global__ void k_scanB(const float* __restrict__ aprod, const float* __restrict__ hend,
                        float* __restrict__ hinit) {
  int i = blockIdx.x * 256 + threadIdx.x;
  float h = 0.0f;
  for (int c = 0; c < NCHUNK; c++) {
    long idx = (long)c * D_INNER * 16 + i;
    hinit[idx] = h;
    h = aprod[idx] * h + hend[idx];
  }
}

// phase C fused with y*silu(z) -> bf16
__global__ void k_scanC(const float* __restrict__ dt, const u16* __restrict__ xi,
                        const float* __restrict__ xdbl, const float* __restrict__ a_log,
                        const float* __restrict__ hinit, const float* __restrict__ Dp,
                        const u16* __restrict__ xzb, u16* __restrict__ yb) {
  int d = blockIdx.x * 256 + threadIdx.x;
  int c = blockIdx.y;
  float A[16], h[16];
  long hb = (long)c * D_INNER * 16 + (long)d * 16;
#pragma unroll
  for (int s = 0; s < 16; s++) { A[s] = -__expf(a_log[d * 16 + s]); h[s] = hinit[hb + s]; }
  float Dv = Dp[d];
  int t0 = c * TCHUNK;
  for (int t = t0; t < t0 + TCHUNK; t++) {
    float dtv = dt[(long)t * D_INNER + d], xv = bf2f(xi[(long)t * D_INNER + d]);
    float dx = dtv * xv;
    const float* Bp = xdbl + (long)t * 80 + DT_RANK;
    const float* Cp = Bp + D_STATE;
    float o = xv * Dv;
#pragma unroll
    for (int s = 0; s < 16; s++) {
      float a = __expf(dtv * A[s]);
      h[s] = a * h[s] + dx * Bp[s];
      o += h[s] * Cp[s];
    }
    float z = bf2f(xzb[(long)t * (2 * D_INNER) + D_INNER + d]);
    yb[(long)t * D_INNER + d] = f2bf(o * (z / (1.0f + __expf(-z))));
  }
}

// ---------------- final lse from partials + nll ------------------------------
__global__ void k_lse_final(const float* __restrict__ part, const float* __restrict__ logits,
                            const int* __restrict__ tgt, float* __restrict__ nll,
                            float* __restrict__ msk) {
  int t = blockIdx.x * 256 + threadIdx.x;   // 2048 threads
  float s = 0.0f;
  for (int p = 0; p < 800; p++) s += part[(size_t)p * LSEQ + t];
  float lse = 20.0f + __logf(s);
  int tg = tgt[t];
  float mk = tg >= 0 ? 1.0f : 0.0f;
  int tc = tg < 0 ? 0 : (tg > VOCAB - 1 ? VOCAB - 1 : tg);
  nll[t] = (lse - logits[(size_t)t * VOCAB + tc]) * mk;
  msk[t] = mk;
}

__global__ void k_loss(const float* __restrict__ nll, const float* __restrict__ msk,
                       float* __restrict__ out) {
  int tid = threadIdx.x;
  __shared__ float r1[256], r2[256];
  float a = 0.0f, b = 0.0f;
  for (int i = tid; i < LSEQ; i += 256) { a += nll[i]; b += msk[i]; }
  r1[tid] = a; r2[tid] = b; __syncthreads();
  for (int o = 128; o > 0; o >>= 1) {
    if (tid < o) { r1[tid] += r1[tid + o]; r2[tid] += r2[tid + o]; }
    __syncthreads();
  }
  if (tid == 0) out[0] = r1[0] / fmaxf(r2[0], 1.0f);
}

// =============================================================================
extern "C" void kernel_launch(void* const* d_in, const int* in_sizes, int n_in,
                              void* d_out, int out_size, void* d_ws, size_t ws_size,
                              hipStream_t stream) {
  const int*   idx    = (const int*)d_in[0];
  const int*   tgt    = (const int*)d_in[1];
  const float* emb    = (const float*)d_in[2];
  const float* norm_w = (const float*)d_in[3];
  const float* in_w   = (const float*)d_in[4];
  const float* conv_w = (const float*)d_in[5];
  const float* conv_b = (const float*)d_in[6];
  const float* xp_w   = (const float*)d_in[7];
  const float* dt_w   = (const float*)d_in[8];
  const float* dt_b   = (const float*)d_in[9];
  const float* a_log  = (const float*)d_in[10];
  const float* d_par  = (const float*)d_in[11];
  const float* out_w  = (const float*)d_in[12];
  const float* normf  = (const float*)d_in[13];

  float* logits = (float*)d_out;
  float* loss   = logits + (size_t)LSEQ * VOCAB;

  char* base = (char*)d_ws;
  size_t off = 0;
  auto alloc = [&](size_t bytes) -> char* {
    char* r = base + off;
    off = (off + bytes + 255) & ~(size_t)255;
    return r;
  };
  u16*   wcat = (u16*)  alloc((size_t)TOTCVT * 2);
  float* x    = (float*)alloc((size_t)LSEQ * D_MODEL * 4);
  u16*   xnb  = (u16*)  alloc((size_t)LSEQ * D_MODEL * 2);
  u16*   xzb  = (u16*)  alloc((size_t)LSEQ * 2 * D_INNER * 2);
  u16*   xib  = (u16*)  alloc((size_t)LSEQ * D_INNER * 2);
  float* xdbl = (float*)alloc((size_t)LSEQ * 80 * 4);
  u16*   dtp  = (u16*)  alloc((size_t)LSEQ * 64 * 2);
  float* dtl  = (float*)alloc((size_t)LSEQ * D_INNER * 4);
  u16*   yb   = (u16*)  alloc((size_t)LSEQ * D_INNER * 2);
  float* pxp  = (float*)alloc((size_t)8 * LSEQ * 80 * 4);
  float* pop  = (float*)alloc((size_t)4 * LSEQ * D_MODEL * 4);
  float* apr  = (float*)alloc((size_t)NCHUNK * D_INNER * 16 * 4);
  float* hen  = (float*)alloc((size_t)NCHUNK * D_INNER * 16 * 4);
  float* hin  = (float*)alloc((size_t)NCHUNK * D_INNER * 16 * 4);
  float* nll  = (float*)alloc((size_t)LSEQ * 4);
  float* msk  = (float*)alloc((size_t)LSEQ * 4);
  float* part = pop;  // alias: logits phase runs after pop's last use
  (void)ws_size; (void)in_sizes; (void)n_in; (void)out_size;

  const u16* embb = wcat;

  k_convert_all<<<(unsigned)(TOTCVT / 256), 256, 0, stream>>>(emb, in_w, xp_w, dt_w, out_w, wcat);
  k_embed_rms<<<LSEQ, 256, 0, stream>>>(idx, emb, norm_w, x, xnb);

  for (int l = 0; l < N_LAYER; l++) {
    const u16* w1 = wcat + EMB_E + (long)l * PERL;
    const u16* w2 = w1 + W1E;
    const u16* w3 = w2 + W2E;
    const u16* w4 = w3 + W3E;

    k_gemm2<2><<<dim3(24, 16), 256, 0, stream>>>(
        xnb, w1, xzb, nullptr, 2 * D_INNER, D_MODEL, D_MODEL, D_MODEL, 2 * D_INNER);

    k_conv_silu<<<(LSEQ * D_INNER) / 256, 256, 0, stream>>>(
        xzb, conv_w + (long)l * D_INNER * 4, conv_b + l * D_INNER, xib);

    k_gemm_part<<<dim3(1, 16, 8), 256, 0, stream>>>(
        xib, w2, pxp, 80, D_INNER / 8, D_INNER, D_INNER, 80);
    k_red_xd<<<(LSEQ * 128) / 256, 256, 0, stream>>>(pxp, xdbl, dtp);

    k_gemm2<1><<<dim3(12, 16), 256, 0, stream>>>(
        dtp, w3, dtl, dt_b + l * D_INNER, D_INNER, 64, 64, 64, D_INNER);

    const float* al = a_log + (long)l * D_INNER * D_STATE;
    k_scanA<<<dim3(D_INNER / 256, NCHUNK), 256, 0, stream>>>(dtl, xib, xdbl, al, apr, hen);
    k_scanB<<<(D_INNER * 16) / 256, 256, 0, stream>>>(apr, hen, hin);
    k_scanC<<<dim3(D_INNER / 256, NCHUNK), 256, 0, stream>>>(
        dtl, xib, xdbl, al, hin, d_par + l * D_INNER, xzb, yb);

    k_gemm_part<<<dim3(6, 16, 4), 256, 0, stream>>>(
        yb, w4, pop, D_MODEL, D_INNER / 4, D_INNER, D_INNER, D_MODEL);

    const float* wn = (l < N_LAYER - 1) ? (norm_w + (l + 1) * D_MODEL) : normf;
    k_rms_red<<<LSEQ, 256, 0, stream>>>(pop, wn, x, xnb);
  }

  k_gemm_logits<<<400 * 16, 256, 0, stream>>>(xnb, embb, logits, part);
  k_lse_final<<<LSEQ / 256, 256, 0, stream>>>(part, logits, tgt, nll, msk);
  k_loss<<<1, 256, 0, stream>>>(nll, msk, loss);
}

// Round 4
// 1209.764 us; speedup vs baseline: 1.3698x; 1.1474x over previous
//
#include <hip/hip_runtime.h>
#include <stdint.h>

// Mamba forward, MI355X. Round 4:
//  - ALL GEMMs: counted-vmcnt pipeline (T4): raw s_barrier, vmcnt(4) steady
//    state (never 0 in loop), loads stay in flight across barriers
//  - logits GEMM keeps XCD-bijective swizzle + fused exp-sum partials
//  - conv1d vectorized (short8 loads, 8 ch/thread)
//  - upfront single convert kernel; fused epilogues as round 3

#define D_MODEL 768
#define N_LAYER 4
#define VOCAB 50257
#define D_STATE 16
#define D_INNER 1536
#define DT_RANK 48
#define LSEQ 2048
#define TCHUNK 64
#define NCHUNK 32

#define EMB_E 39321600L            // 51200*768
#define W1E 2359296L               // 3072*768
#define W2E 196608L                // 128*1536
#define W3E 98304L                 // 1536*64
#define W4E 1179648L               // 768*1536
#define PERL (W1E + W2E + W3E + W4E)
#define TOTCVT (EMB_E + 4 * PERL)

typedef unsigned short u16;
typedef __attribute__((ext_vector_type(8))) short short8;
typedef __attribute__((ext_vector_type(4))) float f32x4;

__device__ __forceinline__ u16 f2bf(float f) {
  unsigned int x = __float_as_uint(f);
  x += 0x7fffu + ((x >> 16) & 1u);   // RNE
  return (u16)(x >> 16);
}
__device__ __forceinline__ float bf2f(u16 v) {
  return __uint_as_float(((unsigned int)v) << 16);
}
__device__ __forceinline__ void gl16(const void* g, void* l) {
  __builtin_amdgcn_global_load_lds((const __attribute__((address_space(1))) void*)g,
                                   (__attribute__((address_space(3))) void*)l, 16, 0, 0);
}

// Counted-vmcnt double-buffered K-loop. Requires in scope:
//   lA,lB ([2][4096] u16 LDS), STAGE(k0,buf), wm,wn,fr,kh, acc[4][4].
// Steady state: 8 loads outstanding (tiles t, t+1); vmcnt(4) waits only for
// the 4 oldest (tile t). No vmcnt(0) until the last iteration.
#define PIPELINE(NT)                                                          \
  STAGE(0, 0);                                                                \
  STAGE(32, 1);                                                               \
  {                                                                           \
    int cur = 0;                                                              \
    for (int t = 0; t < (NT); t++) {                                          \
      if (t + 1 < (NT)) { asm volatile("s_waitcnt vmcnt(4)" ::: "memory"); }  \
      else              { asm volatile("s_waitcnt vmcnt(0)" ::: "memory"); }  \
      asm volatile("s_barrier" ::: "memory");                                 \
      short8 af[4], bfr[4];                                                   \
      _Pragma("unroll")                                                       \
      for (int i = 0; i < 4; i++)                                             \
        af[i] = *(const short8*)(&lA[cur][(wm + i * 16 + fr) * 32 + kh]);     \
      _Pragma("unroll")                                                       \
      for (int j = 0; j < 4; j++)                                             \
        bfr[j] = *(const short8*)(&lB[cur][(wn + j * 16 + fr) * 32 + kh]);    \
      asm volatile("s_waitcnt lgkmcnt(0)" ::: "memory");                      \
      asm volatile("s_barrier" ::: "memory");                                 \
      if (t + 2 < (NT)) STAGE((t + 2) * 32, cur);                             \
      _Pragma("unroll")                                                       \
      for (int i = 0; i < 4; i++)                                             \
        _Pragma("unroll")                                                     \
        for (int j = 0; j < 4; j++)                                           \
          acc[i][j] = __builtin_amdgcn_mfma_f32_16x16x32_bf16(af[i], bfr[j],  \
                                                              acc[i][j], 0, 0, 0); \
      cur ^= 1;                                                               \
    }                                                                         \
  }

// ---------------- upfront convert: emb + all layer weights -> bf16 arena -----
__global__ void k_convert_all(const float* __restrict__ emb, const float* __restrict__ in_w,
                              const float* __restrict__ xp_w, const float* __restrict__ dt_w,
                              const float* __restrict__ out_w, u16* __restrict__ dst) {
  long i = (long)blockIdx.x * 256 + threadIdx.x;
  float v;
  if (i < EMB_E) {
    long n = i / D_MODEL, k = i % D_MODEL;
    v = (n < VOCAB) ? emb[n * D_MODEL + k] : 0.0f;
  } else {
    long j = i - EMB_E;
    int l = (int)(j / PERL);
    long m = j % PERL;
    if (m < W1E) {
      v = in_w[(long)l * W1E + m];
    } else if (m < W1E + W2E) {
      long mm = m - W1E;
      long n = mm / D_INNER, k = mm % D_INNER;
      v = (n < 80) ? xp_w[(long)l * 80 * D_INNER + n * D_INNER + k] : 0.0f;
    } else if (m < W1E + W2E + W3E) {
      long mm = m - (W1E + W2E);
      long n = mm / 64, k = mm % 64;
      v = (k < DT_RANK) ? dt_w[(long)l * D_INNER * DT_RANK + n * DT_RANK + k] : 0.0f;
    } else {
      long mm = m - (W1E + W2E + W3E);
      v = out_w[(long)l * W4E + mm];
    }
  }
  dst[i] = f2bf(v);
}

// ---------------- embed + rmsnorm(layer0) ------------------------------------
__global__ void k_embed_rms(const int* __restrict__ idx, const float* __restrict__ emb,
                            const float* __restrict__ w, float* __restrict__ x,
                            u16* __restrict__ xnb) {
  int t = blockIdx.x, tid = threadIdx.x;
  __shared__ float red[256];
  const float* src = emb + (long)idx[t] * D_MODEL;
  float g[3];
  float s = 0.0f;
#pragma unroll
  for (int q = 0; q < 3; q++) {
    g[q] = src[tid + q * 256];
    s += g[q] * g[q];
  }
  red[tid] = s; __syncthreads();
  for (int o = 128; o > 0; o >>= 1) { if (tid < o) red[tid] += red[tid + o]; __syncthreads(); }
  float scale = rsqrtf(red[0] / (float)D_MODEL + 1e-5f);
#pragma unroll
  for (int q = 0; q < 3; q++) {
    int c = tid + q * 256;
    x[(long)t * D_MODEL + c] = g[q];
    xnb[(long)t * D_MODEL + c] = f2bf(g[q] * scale * w[c]);
  }
}

// ---------------- reduce out_proj partials + residual + rmsnorm --------------
__global__ void k_rms_red(const float* __restrict__ part, const float* __restrict__ w,
                          float* __restrict__ x, u16* __restrict__ xnb) {
  int t = blockIdx.x, tid = threadIdx.x;
  __shared__ float red[256];
  float g[3];
  float s = 0.0f;
#pragma unroll
  for (int q = 0; q < 3; q++) {
    int c = tid + q * 256;
    long off = (long)t * D_MODEL + c;
    float v = x[off];
#pragma unroll
    for (int p = 0; p < 4; p++) v += part[(size_t)p * LSEQ * D_MODEL + off];
    g[q] = v;
    s += v * v;
  }
  red[tid] = s; __syncthreads();
  for (int o = 128; o > 0; o >>= 1) { if (tid < o) red[tid] += red[tid + o]; __syncthreads(); }
  float scale = rsqrtf(red[0] / (float)D_MODEL + 1e-5f);
#pragma unroll
  for (int q = 0; q < 3; q++) {
    int c = tid + q * 256;
    x[(long)t * D_MODEL + c] = g[q];
    xnb[(long)t * D_MODEL + c] = f2bf(g[q] * scale * w[c]);
  }
}

// ---------------- 2-phase counted-vmcnt GEMM: C = A(M,K) * W(N,K)^T ----------
// EPI: 1 = softplus(acc+bias[col]) -> fp32, 2 = bf16 store
template<int EPI>
__global__ __launch_bounds__(256) void k_gemm2(
    const u16* __restrict__ A, const u16* __restrict__ W, void* __restrict__ Cv,
    const float* __restrict__ bias, int N, int K, int lda, int ldb, int ldc) {
  __shared__ u16 lA[2][128 * 32];
  __shared__ u16 lB[2][128 * 32];
  const int gx = gridDim.x, gy = gridDim.y;
  int id = blockIdx.x + gx * blockIdx.y;
  int q8 = (gx * gy) >> 3;
  int v = (id & 7) * q8 + (id >> 3);
  const int bx = v / gy, by = v % gy;
  const int brow = by * 128, bcol = bx * 128;
  const int tid = threadIdx.x, wid = tid >> 6, lane = tid & 63;
  const int wm = (wid >> 1) * 64, wn = (wid & 1) * 64;
  const int fr = lane & 15, fq = lane >> 4, kh = fq * 8;
  const int srow = tid >> 2, scol = (tid & 3) * 8;
  const u16* ga0 = A + (size_t)(brow + srow) * lda + scol;
  const u16* ga1 = A + (size_t)(brow + srow + 64) * lda + scol;
  const u16* gb0 = W + (size_t)(bcol + srow) * ldb + scol;
  const u16* gb1 = W + (size_t)(bcol + srow + 64) * ldb + scol;
  const int lo = srow * 32 + scol;

  f32x4 acc[4][4];
#pragma unroll
  for (int i = 0; i < 4; i++)
#pragma unroll
    for (int j = 0; j < 4; j++)
#pragma unroll
      for (int r = 0; r < 4; r++) acc[i][j][r] = 0.0f;

  auto STAGE = [&](int k0, int b) {
    gl16(ga0 + k0, &lA[b][lo]);
    gl16(ga1 + k0, &lA[b][lo + 2048]);
    gl16(gb0 + k0, &lB[b][lo]);
    gl16(gb1 + k0, &lB[b][lo + 2048]);
  };

  PIPELINE(K / 32);

#pragma unroll
  for (int i = 0; i < 4; i++)
#pragma unroll
    for (int j = 0; j < 4; j++) {
      int col = bcol + wn + j * 16 + fr;
      if (col < N) {
#pragma unroll
        for (int r = 0; r < 4; r++) {
          int row = brow + wm + i * 16 + fq * 4 + r;
          float val = acc[i][j][r];
          if (EPI == 1) {
            val += bias[col];
            val = (val > 20.0f) ? val : log1pf(__expf(val));
            ((float*)Cv)[(size_t)row * ldc + col] = val;
          } else {
            ((u16*)Cv)[(size_t)row * ldc + col] = f2bf(val);
          }
        }
      }
    }
}

// ---------------- split-K partial GEMM ---------------------------------------
__global__ __launch_bounds__(256) void k_gemm_part(
    const u16* __restrict__ A, const u16* __restrict__ W, float* __restrict__ Cp,
    int N, int Ks, int lda, int ldb, int ldc) {
  __shared__ u16 lA[2][128 * 32];
  __shared__ u16 lB[2][128 * 32];
  const int gx = gridDim.x, gy = gridDim.y;
  int id = blockIdx.x + gx * blockIdx.y;
  int q8 = (gx * gy) >> 3;
  int v = (id & 7) * q8 + (id >> 3);
  const int bx = v / gy, by = v % gy;
  const int brow = by * 128, bcol = bx * 128;
  const int koff = blockIdx.z * Ks;
  const int tid = threadIdx.x, wid = tid >> 6, lane = tid & 63;
  const int wm = (wid >> 1) * 64, wn = (wid & 1) * 64;
  const int fr = lane & 15, fq = lane >> 4, kh = fq * 8;
  const int srow = tid >> 2, scol = (tid & 3) * 8;
  const u16* ga0 = A + (size_t)(brow + srow) * lda + koff + scol;
  const u16* ga1 = A + (size_t)(brow + srow + 64) * lda + koff + scol;
  const u16* gb0 = W + (size_t)(bcol + srow) * ldb + koff + scol;
  const u16* gb1 = W + (size_t)(bcol + srow + 64) * ldb + koff + scol;
  const int lo = srow * 32 + scol;

  f32x4 acc[4][4];
#pragma unroll
  for (int i = 0; i < 4; i++)
#pragma unroll
    for (int j = 0; j < 4; j++)
#pragma unroll
      for (int r = 0; r < 4; r++) acc[i][j][r] = 0.0f;

  auto STAGE = [&](int k0, int b) {
    gl16(ga0 + k0, &lA[b][lo]);
    gl16(ga1 + k0, &lA[b][lo + 2048]);
    gl16(gb0 + k0, &lB[b][lo]);
    gl16(gb1 + k0, &lB[b][lo + 2048]);
  };

  PIPELINE(Ks / 32);

  float* Cz = Cp + (size_t)blockIdx.z * LSEQ * ldc;
#pragma unroll
  for (int i = 0; i < 4; i++)
#pragma unroll
    for (int j = 0; j < 4; j++) {
      int col = bcol + wn + j * 16 + fr;
      if (col < N) {
#pragma unroll
        for (int r = 0; r < 4; r++) {
          int row = brow + wm + i * 16 + fq * 4 + r;
          Cz[(size_t)row * ldc + col] = acc[i][j][r];
        }
      }
    }
}

// ---------------- logits GEMM + fused exp-sum partials -----------------------
__global__ __launch_bounds__(256) void k_gemm_logits(
    const u16* __restrict__ A, const u16* __restrict__ W, float* __restrict__ C,
    float* __restrict__ part) {
  __shared__ u16 lA[2][128 * 32];
  __shared__ u16 lB[2][128 * 32];
  const int b = blockIdx.x;
  const int xcd = b & 7, slot = b >> 3;
  const int ct = xcd * 50 + (slot >> 4), rt = slot & 15;
  const int brow = rt * 128, bcol = ct * 128;
  const int tid = threadIdx.x, wid = tid >> 6, lane = tid & 63;
  const int wm = (wid >> 1) * 64, wn = (wid & 1) * 64;
  const int fr = lane & 15, fq = lane >> 4, kh = fq * 8;
  const int srow = tid >> 2, scol = (tid & 3) * 8;
  const u16* ga0 = A + (size_t)(brow + srow) * D_MODEL + scol;
  const u16* ga1 = A + (size_t)(brow + srow + 64) * D_MODEL + scol;
  const u16* gb0 = W + (size_t)(bcol + srow) * D_MODEL + scol;
  const u16* gb1 = W + (size_t)(bcol + srow + 64) * D_MODEL + scol;
  const int lo = srow * 32 + scol;

  f32x4 acc[4][4];
#pragma unroll
  for (int i = 0; i < 4; i++)
#pragma unroll
    for (int j = 0; j < 4; j++)
#pragma unroll
      for (int r = 0; r < 4; r++) acc[i][j][r] = 0.0f;

  auto STAGE = [&](int k0, int bb) {
    gl16(ga0 + k0, &lA[bb][lo]);
    gl16(ga1 + k0, &lA[bb][lo + 2048]);
    gl16(gb0 + k0, &lB[bb][lo]);
    gl16(gb1 + k0, &lB[bb][lo + 2048]);
  };

  PIPELINE(D_MODEL / 32);

  float rs[16];
#pragma unroll
  for (int q = 0; q < 16; q++) rs[q] = 0.0f;
#pragma unroll
  for (int i = 0; i < 4; i++)
#pragma unroll
    for (int j = 0; j < 4; j++) {
      int col = bcol + wn + j * 16 + fr;
      if (col < VOCAB) {
#pragma unroll
        for (int r = 0; r < 4; r++) {
          int row = brow + wm + i * 16 + fq * 4 + r;
          float val = acc[i][j][r];
          C[(size_t)row * VOCAB + col] = val;
          rs[i * 4 + r] += __expf(val - 20.0f);
        }
      }
    }
#pragma unroll
  for (int q = 0; q < 16; q++) {
    float s = rs[q];
    s += __shfl_xor(s, 1); s += __shfl_xor(s, 2);
    s += __shfl_xor(s, 4); s += __shfl_xor(s, 8);
    rs[q] = s;
  }
  if (fr == 0) {
    int pc = ct * 2 + (wn >> 6);
#pragma unroll
    for (int i = 0; i < 4; i++)
#pragma unroll
      for (int r = 0; r < 4; r++) {
        int row = brow + wm + i * 16 + fq * 4 + r;
        part[(size_t)pc * LSEQ + row] = rs[i * 4 + r];
      }
  }
}

// ---------------- causal conv1d (K=4) + silu -> bf16, vectorized x8 ----------
__global__ void k_conv_silu(const u16* __restrict__ xzb, const float* __restrict__ cw,
                            const float* __restrict__ cb, u16* __restrict__ xib) {
  int i = blockIdx.x * 256 + threadIdx.x;      // L * D_INNER/8 threads
  int t = i / (D_INNER / 8), d8 = (i % (D_INNER / 8)) * 8;
  float acc[8];
#pragma unroll
  for (int q = 0; q < 8; q++) acc[q] = cb[d8 + q];
#pragma unroll
  for (int k = 0; k < 4; k++) {
    int tt = t - 3 + k;
    if (tt >= 0) {
      short8 v = *(const short8*)(xzb + (long)tt * (2 * D_INNER) + d8);
#pragma unroll
      for (int q = 0; q < 8; q++) acc[q] += bf2f((u16)v[q]) * cw[(d8 + q) * 4 + k];
    }
  }
  short8 o;
#pragma unroll
  for (int q = 0; q < 8; q++) {
    float s = acc[q] / (1.0f + __expf(-acc[q]));
    o[q] = (short)f2bf(s);
  }
  *(short8*)(xib + (long)t * D_INNER + d8) = o;
}

// ---------------- reduce x_proj partials -> xdbl + dt-pad bf16 ---------------
__global__ void k_red_xd(const float* __restrict__ pxp, float* __restrict__ xdbl,
                         u16* __restrict__ dtp) {
  int i = blockIdx.x * 256 + threadIdx.x;
  int t = i >> 7, k = i & 127;
  if (k < 80) {
    float s = 0.0f;
#pragma unroll
    for (int p = 0; p < 8; p++) s += pxp[(size_t)p * LSEQ * 80 + (long)t * 80 + k];
    xdbl[(long)t * 80 + k] = s;
    if (k < DT_RANK) dtp[(long)t * 64 + k] = f2bf(s);
    else if (k < 64) dtp[(long)t * 64 + k] = 0;
  }
}

// ---------------- selective scan: 3-phase chunked ----------------------------
__global__ void k_scanA(const float* __restrict__ dt, const u16* __restrict__ xi,
                        const float* __restrict__ xdbl, const float* __restrict__ a_log,
                        float* __restrict__ aprod, float* __restrict__ hend) {
  int d = blockIdx.x * 256 + threadIdx.x;
  int c = blockIdx.y;
  float A[16], ap[16], h[16];
#pragma unroll
  for (int s = 0; s < 16; s++) { A[s] = -__expf(a_log[d * 16 + s]); ap[s] = 1.0f; h[s] = 0.0f; }
  int t0 = c * TCHUNK;
  for (int t = t0; t < t0 + TCHUNK; t++) {
    float dtv = dt[(long)t * D_INNER + d], xv = bf2f(xi[(long)t * D_INNER + d]);
    float dx = dtv * xv;
    const float* Bp = xdbl + (long)t * 80 + DT_RANK;
#pragma unroll
    for (int s = 0; s < 16; s++) {
      float a = __expf(dtv * A[s]);
      h[s] = a * h[s] + dx * Bp[s];
      ap[s] *= a;
    }
  }
  long base = ((long)c * D_INNER + d) * 16;
#pragma unroll
  for (int s = 0; s < 16; s++) { aprod[base + s] = ap[s]; hend[base + s] = h[s]; }
}

__global__ void k_scanB(const float* __restrict__ aprod, const float* __restrict__ hend,
                        float* __restrict__ hinit) {
  int i = blockIdx.x * 256 + threadIdx.x;
  float h = 0.0f;
  for (int c = 0; c < NCHUNK; c++) {
    long idx = (long)c * D_INNER * 16 + i;
    hinit[idx] = h;
    h = aprod[idx] * h + hend[idx];
  }
}

__global__ void k_scanC(const float* __restrict__ dt, const u16* __restrict__ xi,
                        const float* __restrict__ xdbl, const float* __restrict__ a_log,
                        const float* __restrict__ hinit, const float* __restrict__ Dp,
                        const u16* __restrict__ xzb, u16* __restrict__ yb) {
  int d = blockIdx.x * 256 + threadIdx.x;
  int c = blockIdx.y;
  float A[16], h[16];
  long hb = (long)c * D_INNER * 16 + (long)d * 16;
#pragma unroll
  for (int s = 0; s < 16; s++) { A[s] = -__expf(a_log[d * 16 + s]); h[s] = hinit[hb + s]; }
  float Dv = Dp[d];
  int t0 = c * TCHUNK;
  for (int t = t0; t < t0 + TCHUNK; t++) {
    float dtv = dt[(long)t * D_INNER + d], xv = bf2f(xi[(long)t * D_INNER + d]);
    float dx = dtv * xv;
    const float* Bp = xdbl + (long)t * 80 + DT_RANK;
    const float* Cp = Bp + D_STATE;
    float o = xv * Dv;
#pragma unroll
    for (int s = 0; s < 16; s++) {
      float a = __expf(dtv * A[s]);
      h[s] = a * h[s] + dx * Bp[s];
      o += h[s] * Cp[s];
    }
    float z = bf2f(xzb[(long)t * (2 * D_INNER) + D_INNER + d]);
    yb[(long)t * D_INNER + d] = f2bf(o * (z / (1.0f + __expf(-z))));
  }
}

// ---------------- final lse from partials + nll ------------------------------
__global__ void k_lse_final(const float* __restrict__ part, const float* __restrict__ logits,
                            const int* __restrict__ tgt, float* __restrict__ nll,
                            float* __restrict__ msk) {
  int t = blockIdx.x * 256 + threadIdx.x;
  float s = 0.0f;
  for (int p = 0; p < 800; p++) s += part[(size_t)p * LSEQ + t];
  float lse = 20.0f + __logf(s);
  int tg = tgt[t];
  float mk = tg >= 0 ? 1.0f : 0.0f;
  int tc = tg < 0 ? 0 : (tg > VOCAB - 1 ? VOCAB - 1 : tg);
  nll[t] = (lse - logits[(size_t)t * VOCAB + tc]) * mk;
  msk[t] = mk;
}

__global__ void k_loss(const float* __restrict__ nll, const float* __restrict__ msk,
                       float* __restrict__ out) {
  int tid = threadIdx.x;
  __shared__ float r1[256], r2[256];
  float a = 0.0f, b = 0.0f;
  for (int i = tid; i < LSEQ; i += 256) { a += nll[i]; b += msk[i]; }
  r1[tid] = a; r2[tid] = b; __syncthreads();
  for (int o = 128; o > 0; o >>= 1) {
    if (tid < o) { r1[tid] += r1[tid + o]; r2[tid] += r2[tid + o]; }
    __syncthreads();
  }
  if (tid == 0) out[0] = r1[0] / fmaxf(r2[0], 1.0f);
}

// =============================================================================
extern "C" void kernel_launch(void* const* d_in, const int* in_sizes, int n_in,
                              void* d_out, int out_size, void* d_ws, size_t ws_size,
                              hipStream_t stream) {
  const int*   idx    = (const int*)d_in[0];
  const int*   tgt    = (const int*)d_in[1];
  const float* emb    = (const float*)d_in[2];
  const float* norm_w = (const float*)d_in[3];
  const float* in_w   = (const float*)d_in[4];
  const float* conv_w = (const float*)d_in[5];
  const float* conv_b = (const float*)d_in[6];
  const float* xp_w   = (const float*)d_in[7];
  const float* dt_w   = (const float*)d_in[8];
  const float* dt_b   = (const float*)d_in[9];
  const float* a_log  = (const float*)d_in[10];
  const float* d_par  = (const float*)d_in[11];
  const float* out_w  = (const float*)d_in[12];
  const float* normf  = (const float*)d_in[13];

  float* logits = (float*)d_out;
  float* loss   = logits + (size_t)LSEQ * VOCAB;

  char* base = (char*)d_ws;
  size_t off = 0;
  auto alloc = [&](size_t bytes) -> char* {
    char* r = base + off;
    off = (off + bytes + 255) & ~(size_t)255;
    return r;
  };
  u16*   wcat = (u16*)  alloc((size_t)TOTCVT * 2);
  float* x    = (float*)alloc((size_t)LSEQ * D_MODEL * 4);
  u16*   xnb  = (u16*)  alloc((size_t)LSEQ * D_MODEL * 2);
  u16*   xzb  = (u16*)  alloc((size_t)LSEQ * 2 * D_INNER * 2);
  u16*   xib  = (u16*)  alloc((size_t)LSEQ * D_INNER * 2);
  float* xdbl = (float*)alloc((size_t)LSEQ * 80 * 4);
  u16*   dtp  = (u16*)  alloc((size_t)LSEQ * 64 * 2);
  float* dtl  = (float*)alloc((size_t)LSEQ * D_INNER * 4);
  u16*   yb   = (u16*)  alloc((size_t)LSEQ * D_INNER * 2);
  float* pxp  = (float*)alloc((size_t)8 * LSEQ * 80 * 4);
  float* pop  = (float*)alloc((size_t)4 * LSEQ * D_MODEL * 4);
  float* apr  = (float*)alloc((size_t)NCHUNK * D_INNER * 16 * 4);
  float* hen  = (float*)alloc((size_t)NCHUNK * D_INNER * 16 * 4);
  float* hin  = (float*)alloc((size_t)NCHUNK * D_INNER * 16 * 4);
  float* nll  = (float*)alloc((size_t)LSEQ * 4);
  float* msk  = (float*)alloc((size_t)LSEQ * 4);
  float* part = pop;  // alias: logits phase runs after pop's last use
  (void)ws_size; (void)in_sizes; (void)n_in; (void)out_size;

  const u16* embb = wcat;

  k_convert_all<<<(unsigned)(TOTCVT / 256), 256, 0, stream>>>(emb, in_w, xp_w, dt_w, out_w, wcat);
  k_embed_rms<<<LSEQ, 256, 0, stream>>>(idx, emb, norm_w, x, xnb);

  for (int l = 0; l < N_LAYER; l++) {
    const u16* w1 = wcat + EMB_E + (long)l * PERL;
    const u16* w2 = w1 + W1E;
    const u16* w3 = w2 + W2E;
    const u16* w4 = w3 + W3E;

    k_gemm2<2><<<dim3(24, 16), 256, 0, stream>>>(
        xnb, w1, xzb, nullptr, 2 * D_INNER, D_MODEL, D_MODEL, D_MODEL, 2 * D_INNER);

    k_conv_silu<<<(LSEQ * D_INNER / 8) / 256, 256, 0, stream>>>(
        xzb, conv_w + (long)l * D_INNER * 4, conv_b + l * D_INNER, xib);

    k_gemm_part<<<dim3(1, 16, 8), 256, 0, stream>>>(
        xib, w2, pxp, 80, D_INNER / 8, D_INNER, D_INNER, 80);
    k_red_xd<<<(LSEQ * 128) / 256, 256, 0, stream>>>(pxp, xdbl, dtp);

    k_gemm2<1><<<dim3(12, 16), 256, 0, stream>>>(
        dtp, w3, dtl, dt_b + l * D_INNER, D_INNER, 64, 64, 64, D_INNER);

    const float* al = a_log + (long)l * D_INNER * D_STATE;
    k_scanA<<<dim3(D_INNER / 256, NCHUNK), 256, 0, stream>>>(dtl, xib, xdbl, al, apr, hen);
    k_scanB<<<(D_INNER * 16) / 256, 256, 0, stream>>>(apr, hen, hin);
    k_scanC<<<dim3(D_INNER / 256, NCHUNK), 256, 0, stream>>>(
        dtl, xib, xdbl, al, hin, d_par + l * D_INNER, xzb, yb);

    k_gemm_part<<<dim3(6, 16, 4), 256, 0, stream>>>(
        yb, w4, pop, D_MODEL, D_INNER / 4, D_INNER, D_INNER, D_MODEL);

    const float* wn = (l < N_LAYER - 1) ? (norm_w + (l + 1) * D_MODEL) : normf;
    k_rms_red<<<LSEQ, 256, 0, stream>>>(pop, wn, x, xnb);
  }

  k_gemm_logits<<<400 * 16, 256, 0, stream>>>(xnb, embb, logits, part);
  k_lse_final<<<LSEQ / 256, 256, 0, stream>>>(part, logits, tgt, nll, msk);
  k_loss<<<1, 256, 0, stream>>>(nll, msk, loss);
}

// Round 5
// 1171.008 us; speedup vs baseline: 1.4151x; 1.0331x over previous
//
#include <hip/hip_runtime.h>
#include <stdint.h>

// Mamba forward, MI355X. Round 5:
//  - T2 XOR slot-swizzle on ALL GEMM LDS tiles (linear LDS dest via
//    global_load_lds + pre-swizzled global source col + swizzled read slot)
//  - logits GEMM: 256x128 tile, 4 waves, per-wave 128x64 (8x4 frags, 32 MFMA
//    per K-step), vmcnt(6) counted pipeline, setprio around MFMA cluster
//  - everything else as round 4

#define D_MODEL 768
#define N_LAYER 4
#define VOCAB 50257
#define D_STATE 16
#define D_INNER 1536
#define DT_RANK 48
#define LSEQ 2048
#define TCHUNK 64
#define NCHUNK 32

#define EMB_E 39321600L            // 51200*768
#define W1E 2359296L               // 3072*768
#define W2E 196608L                // 128*1536
#define W3E 98304L                 // 1536*64
#define W4E 1179648L               // 768*1536
#define PERL (W1E + W2E + W3E + W4E)
#define TOTCVT (EMB_E + 4 * PERL)

typedef unsigned short u16;
typedef __attribute__((ext_vector_type(8))) short short8;
typedef __attribute__((ext_vector_type(4))) float f32x4;

__device__ __forceinline__ u16 f2bf(float f) {
  unsigned int x = __float_as_uint(f);
  x += 0x7fffu + ((x >> 16) & 1u);   // RNE
  return (u16)(x >> 16);
}
__device__ __forceinline__ float bf2f(u16 v) {
  return __uint_as_float(((unsigned int)v) << 16);
}
__device__ __forceinline__ void gl16(const void* g, void* l) {
  __builtin_amdgcn_global_load_lds((const __attribute__((address_space(1))) void*)g,
                                   (__attribute__((address_space(3))) void*)l, 16, 0, 0);
}

// Counted-vmcnt double-buffered K-loop (128x128 tile kernels).
// Steady state: 8 loads outstanding; vmcnt(4) waits only for tile t's 4.
#define PIPELINE(NT)                                                          \
  STAGE(0, 0);                                                                \
  STAGE(32, 1);                                                               \
  {                                                                           \
    int cur = 0;                                                              \
    for (int t = 0; t < (NT); t++) {                                          \
      if (t + 1 < (NT)) { asm volatile("s_waitcnt vmcnt(4)" ::: "memory"); }  \
      else              { asm volatile("s_waitcnt vmcnt(0)" ::: "memory"); }  \
      asm volatile("s_barrier" ::: "memory");                                 \
      short8 af[4], bfr[4];                                                   \
      _Pragma("unroll")                                                       \
      for (int i = 0; i < 4; i++)                                             \
        af[i] = *(const short8*)(&lA[cur][(wm + i * 16 + fr) * 32 + kh]);     \
      _Pragma("unroll")                                                       \
      for (int j = 0; j < 4; j++)                                             \
        bfr[j] = *(const short8*)(&lB[cur][(wn + j * 16 + fr) * 32 + kh]);    \
      asm volatile("s_waitcnt lgkmcnt(0)" ::: "memory");                      \
      asm volatile("s_barrier" ::: "memory");                                 \
      if (t + 2 < (NT)) STAGE((t + 2) * 32, cur);                             \
      _Pragma("unroll")                                                       \
      for (int i = 0; i < 4; i++)                                             \
        _Pragma("unroll")                                                     \
        for (int j = 0; j < 4; j++)                                           \
          acc[i][j] = __builtin_amdgcn_mfma_f32_16x16x32_bf16(af[i], bfr[j],  \
                                                              acc[i][j], 0, 0, 0); \
      cur ^= 1;                                                               \
    }                                                                         \
  }

// ---------------- upfront convert: emb + all layer weights -> bf16 arena -----
__global__ void k_convert_all(const float* __restrict__ emb, const float* __restrict__ in_w,
                              const float* __restrict__ xp_w, const float* __restrict__ dt_w,
                              const float* __restrict__ out_w, u16* __restrict__ dst) {
  long i = (long)blockIdx.x * 256 + threadIdx.x;
  float v;
  if (i < EMB_E) {
    long n = i / D_MODEL, k = i % D_MODEL;
    v = (n < VOCAB) ? emb[n * D_MODEL + k] : 0.0f;
  } else {
    long j = i - EMB_E;
    int l = (int)(j / PERL);
    long m = j % PERL;
    if (m < W1E) {
      v = in_w[(long)l * W1E + m];
    } else if (m < W1E + W2E) {
      long mm = m - W1E;
      long n = mm / D_INNER, k = mm % D_INNER;
      v = (n < 80) ? xp_w[(long)l * 80 * D_INNER + n * D_INNER + k] : 0.0f;
    } else if (m < W1E + W2E + W3E) {
      long mm = m - (W1E + W2E);
      long n = mm / 64, k = mm % 64;
      v = (k < DT_RANK) ? dt_w[(long)l * D_INNER * DT_RANK + n * DT_RANK + k] : 0.0f;
    } else {
      long mm = m - (W1E + W2E + W3E);
      v = out_w[(long)l * W4E + mm];
    }
  }
  dst[i] = f2bf(v);
}

// ---------------- embed + rmsnorm(layer0) ------------------------------------
__global__ void k_embed_rms(const int* __restrict__ idx, const float* __restrict__ emb,
                            const float* __restrict__ w, float* __restrict__ x,
                            u16* __restrict__ xnb) {
  int t = blockIdx.x, tid = threadIdx.x;
  __shared__ float red[256];
  const float* src = emb + (long)idx[t] * D_MODEL;
  float g[3];
  float s = 0.0f;
#pragma unroll
  for (int q = 0; q < 3; q++) {
    g[q] = src[tid + q * 256];
    s += g[q] * g[q];
  }
  red[tid] = s; __syncthreads();
  for (int o = 128; o > 0; o >>= 1) { if (tid < o) red[tid] += red[tid + o]; __syncthreads(); }
  float scale = rsqrtf(red[0] / (float)D_MODEL + 1e-5f);
#pragma unroll
  for (int q = 0; q < 3; q++) {
    int c = tid + q * 256;
    x[(long)t * D_MODEL + c] = g[q];
    xnb[(long)t * D_MODEL + c] = f2bf(g[q] * scale * w[c]);
  }
}

// ---------------- reduce out_proj partials + residual + rmsnorm --------------
__global__ void k_rms_red(const float* __restrict__ part, const float* __restrict__ w,
                          float* __restrict__ x, u16* __restrict__ xnb) {
  int t = blockIdx.x, tid = threadIdx.x;
  __shared__ float red[256];
  float g[3];
  float s = 0.0f;
#pragma unroll
  for (int q = 0; q < 3; q++) {
    int c = tid + q * 256;
    long off = (long)t * D_MODEL + c;
    float v = x[off];
#pragma unroll
    for (int p = 0; p < 4; p++) v += part[(size_t)p * LSEQ * D_MODEL + off];
    g[q] = v;
    s += v * v;
  }
  red[tid] = s; __syncthreads();
  for (int o = 128; o > 0; o >>= 1) { if (tid < o) red[tid] += red[tid + o]; __syncthreads(); }
  float scale = rsqrtf(red[0] / (float)D_MODEL + 1e-5f);
#pragma unroll
  for (int q = 0; q < 3; q++) {
    int c = tid + q * 256;
    x[(long)t * D_MODEL + c] = g[q];
    xnb[(long)t * D_MODEL + c] = f2bf(g[q] * scale * w[c]);
  }
}

// ---------------- 128x128 counted-vmcnt GEMM: C = A(M,K) * W(N,K)^T ----------
// EPI: 1 = softplus(acc+bias[col]) -> fp32, 2 = bf16 store
template<int EPI>
__global__ __launch_bounds__(256) void k_gemm2(
    const u16* __restrict__ A, const u16* __restrict__ W, void* __restrict__ Cv,
    const float* __restrict__ bias, int N, int K, int lda, int ldb, int ldc) {
  __shared__ u16 lA[2][128 * 32];
  __shared__ u16 lB[2][128 * 32];
  const int gx = gridDim.x, gy = gridDim.y;
  int id = blockIdx.x + gx * blockIdx.y;
  int q8 = (gx * gy) >> 3;
  int v = (id & 7) * q8 + (id >> 3);
  const int bx = v / gy, by = v % gy;
  const int brow = by * 128, bcol = bx * 128;
  const int tid = threadIdx.x, wid = tid >> 6, lane = tid & 63;
  const int wm = (wid >> 1) * 64, wn = (wid & 1) * 64;
  const int fr = lane & 15, fq = lane >> 4;
  const int kh = 8 * (fq ^ ((fr >> 1) & 3));                    // swizzled read slot
  const int srow = tid >> 2;
  const int lcol = (tid & 3) * 8;                               // linear LDS col
  const int scol = 8 * ((tid & 3) ^ ((srow >> 1) & 3));         // swizzled source col
  const u16* ga0 = A + (size_t)(brow + srow) * lda + scol;
  const u16* ga1 = A + (size_t)(brow + srow + 64) * lda + scol;
  const u16* gb0 = W + (size_t)(bcol + srow) * ldb + scol;
  const u16* gb1 = W + (size_t)(bcol + srow + 64) * ldb + scol;
  const int lo = srow * 32 + lcol;

  f32x4 acc[4][4];
#pragma unroll
  for (int i = 0; i < 4; i++)
#pragma unroll
    for (int j = 0; j < 4; j++)
#pragma unroll
      for (int r = 0; r < 4; r++) acc[i][j][r] = 0.0f;

  auto STAGE = [&](int k0, int b) {
    gl16(ga0 + k0, &lA[b][lo]);
    gl16(ga1 + k0, &lA[b][lo + 2048]);
    gl16(gb0 + k0, &lB[b][lo]);
    gl16(gb1 + k0, &lB[b][lo + 2048]);
  };

  PIPELINE(K / 32);

#pragma unroll
  for (int i = 0; i < 4; i++)
#pragma unroll
    for (int j = 0; j < 4; j++) {
      int col = bcol + wn + j * 16 + fr;
      if (col < N) {
#pragma unroll
        for (int r = 0; r < 4; r++) {
          int row = brow + wm + i * 16 + fq * 4 + r;
          float val = acc[i][j][r];
          if (EPI == 1) {
            val += bias[col];
            val = (val > 20.0f) ? val : log1pf(__expf(val));
            ((float*)Cv)[(size_t)row * ldc + col] = val;
          } else {
            ((u16*)Cv)[(size_t)row * ldc + col] = f2bf(val);
          }
        }
      }
    }
}

// ---------------- split-K partial GEMM ---------------------------------------
__global__ __launch_bounds__(256) void k_gemm_part(
    const u16* __restrict__ A, const u16* __restrict__ W, float* __restrict__ Cp,
    int N, int Ks, int lda, int ldb, int ldc) {
  __shared__ u16 lA[2][128 * 32];
  __shared__ u16 lB[2][128 * 32];
  const int gx = gridDim.x, gy = gridDim.y;
  int id = blockIdx.x + gx * blockIdx.y;
  int q8 = (gx * gy) >> 3;
  int v = (id & 7) * q8 + (id >> 3);
  const int bx = v / gy, by = v % gy;
  const int brow = by * 128, bcol = bx * 128;
  const int koff = blockIdx.z * Ks;
  const int tid = threadIdx.x, wid = tid >> 6, lane = tid & 63;
  const int wm = (wid >> 1) * 64, wn = (wid & 1) * 64;
  const int fr = lane & 15, fq = lane >> 4;
  const int kh = 8 * (fq ^ ((fr >> 1) & 3));
  const int srow = tid >> 2;
  const int lcol = (tid & 3) * 8;
  const int scol = 8 * ((tid & 3) ^ ((srow >> 1) & 3));
  const u16* ga0 = A + (size_t)(brow + srow) * lda + koff + scol;
  const u16* ga1 = A + (size_t)(brow + srow + 64) * lda + koff + scol;
  const u16* gb0 = W + (size_t)(bcol + srow) * ldb + koff + scol;
  const u16* gb1 = W + (size_t)(bcol + srow + 64) * ldb + koff + scol;
  const int lo = srow * 32 + lcol;

  f32x4 acc[4][4];
#pragma unroll
  for (int i = 0; i < 4; i++)
#pragma unroll
    for (int j = 0; j < 4; j++)
#pragma unroll
      for (int r = 0; r < 4; r++) acc[i][j][r] = 0.0f;

  auto STAGE = [&](int k0, int b) {
    gl16(ga0 + k0, &lA[b][lo]);
    gl16(ga1 + k0, &lA[b][lo + 2048]);
    gl16(gb0 + k0, &lB[b][lo]);
    gl16(gb1 + k0, &lB[b][lo + 2048]);
  };

  PIPELINE(Ks / 32);

  float* Cz = Cp + (size_t)blockIdx.z * LSEQ * ldc;
#pragma unroll
  for (int i = 0; i < 4; i++)
#pragma unroll
    for (int j = 0; j < 4; j++) {
      int col = bcol + wn + j * 16 + fr;
      if (col < N) {
#pragma unroll
        for (int r = 0; r < 4; r++) {
          int row = brow + wm + i * 16 + fq * 4 + r;
          Cz[(size_t)row * ldc + col] = acc[i][j][r];
        }
      }
    }
}

// ---------------- logits GEMM: 256x128 tile, per-wave 128x64 -----------------
// 8 row-tiles x 400 col-tiles; ct walked 50/XCD, rt inner (B-panel L2 reuse).
__global__ __launch_bounds__(256, 2) void k_gemm_logits(
    const u16* __restrict__ A, const u16* __restrict__ W, float* __restrict__ C,
    float* __restrict__ part) {
  __shared__ u16 lA[2][256 * 32];
  __shared__ u16 lB[2][128 * 32];
  const int b = blockIdx.x;
  const int xcd = b & 7, slot = b >> 3;
  const int ct = xcd * 50 + (slot >> 3), rt = slot & 7;
  const int brow = rt * 256, bcol = ct * 128;
  const int tid = threadIdx.x, wid = tid >> 6, lane = tid & 63;
  const int wm = (wid >> 1) * 128, wn = (wid & 1) * 64;
  const int fr = lane & 15, fq = lane >> 4;
  const int kh = 8 * (fq ^ ((fr >> 1) & 3));
  const int srow = tid >> 2;
  const int lcol = (tid & 3) * 8;
  const int scol = 8 * ((tid & 3) ^ ((srow >> 1) & 3));
  const u16* ga = A + (size_t)(brow + srow) * D_MODEL + scol;
  const u16* gb = W + (size_t)(bcol + srow) * D_MODEL + scol;
  const int lo = srow * 32 + lcol;

  f32x4 acc[8][4];
#pragma unroll
  for (int i = 0; i < 8; i++)
#pragma unroll
    for (int j = 0; j < 4; j++)
#pragma unroll
      for (int r = 0; r < 4; r++) acc[i][j][r] = 0.0f;

  auto STAGE = [&](int k0, int bb) {
    gl16(ga + k0, &lA[bb][lo]);
    gl16(ga + (size_t)64 * D_MODEL + k0, &lA[bb][lo + 2048]);
    gl16(ga + (size_t)128 * D_MODEL + k0, &lA[bb][lo + 4096]);
    gl16(ga + (size_t)192 * D_MODEL + k0, &lA[bb][lo + 6144]);
    gl16(gb + k0, &lB[bb][lo]);
    gl16(gb + (size_t)64 * D_MODEL + k0, &lB[bb][lo + 2048]);
  };

  STAGE(0, 0);
  STAGE(32, 1);
  int cur = 0;
  const int NT = D_MODEL / 32;
  for (int t = 0; t < NT; t++) {
    if (t + 1 < NT) { asm volatile("s_waitcnt vmcnt(6)" ::: "memory"); }
    else            { asm volatile("s_waitcnt vmcnt(0)" ::: "memory"); }
    asm volatile("s_barrier" ::: "memory");
    short8 af[8], bfr[4];
#pragma unroll
    for (int i = 0; i < 8; i++)
      af[i] = *(const short8*)(&lA[cur][(wm + i * 16 + fr) * 32 + kh]);
#pragma unroll
    for (int j = 0; j < 4; j++)
      bfr[j] = *(const short8*)(&lB[cur][(wn + j * 16 + fr) * 32 + kh]);
    asm volatile("s_waitcnt lgkmcnt(0)" ::: "memory");
    asm volatile("s_barrier" ::: "memory");
    if (t + 2 < NT) STAGE((t + 2) * 32, cur);
    __builtin_amdgcn_s_setprio(1);
#pragma unroll
    for (int i = 0; i < 8; i++)
#pragma unroll
      for (int j = 0; j < 4; j++)
        acc[i][j] = __builtin_amdgcn_mfma_f32_16x16x32_bf16(af[i], bfr[j], acc[i][j], 0, 0, 0);
    __builtin_amdgcn_s_setprio(0);
    cur ^= 1;
  }

  float rs[32];
#pragma unroll
  for (int q = 0; q < 32; q++) rs[q] = 0.0f;
#pragma unroll
  for (int i = 0; i < 8; i++)
#pragma unroll
    for (int j = 0; j < 4; j++) {
      int col = bcol + wn + j * 16 + fr;
      if (col < VOCAB) {
#pragma unroll
        for (int r = 0; r < 4; r++) {
          int row = brow + wm + i * 16 + fq * 4 + r;
          float val = acc[i][j][r];
          C[(size_t)row * VOCAB + col] = val;
          rs[i * 4 + r] += __expf(val - 20.0f);
        }
      }
    }
#pragma unroll
  for (int q = 0; q < 32; q++) {
    float s = rs[q];
    s += __shfl_xor(s, 1); s += __shfl_xor(s, 2);
    s += __shfl_xor(s, 4); s += __shfl_xor(s, 8);
    rs[q] = s;
  }
  if (fr == 0) {
    int pc = ct * 2 + (wn >> 6);
#pragma unroll
    for (int i = 0; i < 8; i++)
#pragma unroll
      for (int r = 0; r < 4; r++) {
        int row = brow + wm + i * 16 + fq * 4 + r;
        part[(size_t)pc * LSEQ + row] = rs[i * 4 + r];
      }
  }
}

// ---------------- causal conv1d (K=4) + silu -> bf16, vectorized x8 ----------
__global__ void k_conv_silu(const u16* __restrict__ xzb, const float* __restrict__ cw,
                            const float* __restrict__ cb, u16* __restrict__ xib) {
  int i = blockIdx.x * 256 + threadIdx.x;      // L * D_INNER/8 threads
  int t = i / (D_INNER / 8), d8 = (i % (D_INNER / 8)) * 8;
  float acc[8];
#pragma unroll
  for (int q = 0; q < 8; q++) acc[q] = cb[d8 + q];
#pragma unroll
  for (int k = 0; k < 4; k++) {
    int tt = t - 3 + k;
    if (tt >= 0) {
      short8 v = *(const short8*)(xzb + (long)tt * (2 * D_INNER) + d8);
#pragma unroll
      for (int q = 0; q < 8; q++) acc[q] += bf2f((u16)v[q]) * cw[(d8 + q) * 4 + k];
    }
  }
  short8 o;
#pragma unroll
  for (int q = 0; q < 8; q++) {
    float s = acc[q] / (1.0f + __expf(-acc[q]));
    o[q] = (short)f2bf(s);
  }
  *(short8*)(xib + (long)t * D_INNER + d8) = o;
}

// ---------------- reduce x_proj partials -> xdbl + dt-pad bf16 ---------------
__global__ void k_red_xd(const float* __restrict__ pxp, float* __restrict__ xdbl,
                         u16* __restrict__ dtp) {
  int i = blockIdx.x * 256 + threadIdx.x;
  int t = i >> 7, k = i & 127;
  if (k < 80) {
    float s = 0.0f;
#pragma unroll
    for (int p = 0; p < 8; p++) s += pxp[(size_t)p * LSEQ * 80 + (long)t * 80 + k];
    xdbl[(long)t * 80 + k] = s;
    if (k < DT_RANK) dtp[(long)t * 64 + k] = f2bf(s);
    else if (k < 64) dtp[(long)t * 64 + k] = 0;
  }
}

// ---------------- selective scan: 3-phase chunked ----------------------------
__global__ void k_scanA(const float* __restrict__ dt, const u16* __restrict__ xi,
                        const float* __restrict__ xdbl, const float* __restrict__ a_log,
                        float* __restrict__ aprod, float* __restrict__ hend) {
  int d = blockIdx.x * 256 + threadIdx.x;
  int c = blockIdx.y;
  float A[16], ap[16], h[16];
#pragma unroll
  for (int s = 0; s < 16; s++) { A[s] = -__expf(a_log[d * 16 + s]); ap[s] = 1.0f; h[s] = 0.0f; }
  int t0 = c * TCHUNK;
  for (int t = t0; t < t0 + TCHUNK; t++) {
    float dtv = dt[(long)t * D_INNER + d], xv = bf2f(xi[(long)t * D_INNER + d]);
    float dx = dtv * xv;
    const float* Bp = xdbl + (long)t * 80 + DT_RANK;
#pragma unroll
    for (int s = 0; s < 16; s++) {
      float a = __expf(dtv * A[s]);
      h[s] = a * h[s] + dx * Bp[s];
      ap[s] *= a;
    }
  }
  long base = ((long)c * D_INNER + d) * 16;
#pragma unroll
  for (int s = 0; s < 16; s++) { aprod[base + s] = ap[s]; hend[base + s] = h[s]; }
}

__global__ void k_scanB(const float* __restrict__ aprod, const float* __restrict__ hend,
                        float* __restrict__ hinit) {
  int i = blockIdx.x * 256 + threadIdx.x;
  float h = 0.0f;
  for (int c = 0; c < NCHUNK; c++) {
    long idx = (long)c * D_INNER * 16 + i;
    hinit[idx] = h;
    h = aprod[idx] * h + hend[idx];
  }
}

__global__ void k_scanC(const float* __restrict__ dt, const u16* __restrict__ xi,
                        const float* __restrict__ xdbl, const float* __restrict__ a_log,
                        const float* __restrict__ hinit, const float* __restrict__ Dp,
                        const u16* __restrict__ xzb, u16* __restrict__ yb) {
  int d = blockIdx.x * 256 + threadIdx.x;
  int c = blockIdx.y;
  float A[16], h[16];
  long hb = (long)c * D_INNER * 16 + (long)d * 16;
#pragma unroll
  for (int s = 0; s < 16; s++) { A[s] = -__expf(a_log[d * 16 + s]); h[s] = hinit[hb + s]; }
  float Dv = Dp[d];
  int t0 = c * TCHUNK;
  for (int t = t0; t < t0 + TCHUNK; t++) {
    float dtv = dt[(long)t * D_INNER + d], xv = bf2f(xi[(long)t * D_INNER + d]);
    float dx = dtv * xv;
    const float* Bp = xdbl + (long)t * 80 + DT_RANK;
    const float* Cp = Bp + D_STATE;
    float o = xv * Dv;
#pragma unroll
    for (int s = 0; s < 16; s++) {
      float a = __expf(dtv * A[s]);
      h[s] = a * h[s] + dx * Bp[s];
      o += h[s] * Cp[s];
    }
    float z = bf2f(xzb[(long)t * (2 * D_INNER) + D_INNER + d]);
    yb[(long)t * D_INNER + d] = f2bf(o * (z / (1.0f + __expf(-z))));
  }
}

// ---------------- final lse from partials + nll ------------------------------
__global__ void k_lse_final(const float* __restrict__ part, const float* __restrict__ logits,
                            const int* __restrict__ tgt, float* __restrict__ nll,
                            float* __restrict__ msk) {
  int t = blockIdx.x * 256 + threadIdx.x;
  float s = 0.0f;
  for (int p = 0; p < 800; p++) s += part[(size_t)p * LSEQ + t];
  float lse = 20.0f + __logf(s);
  int tg = tgt[t];
  float mk = tg >= 0 ? 1.0f : 0.0f;
  int tc = tg < 0 ? 0 : (tg > VOCAB - 1 ? VOCAB - 1 : tg);
  nll[t] = (lse - logits[(size_t)t * VOCAB + tc]) * mk;
  msk[t] = mk;
}

__global__ void k_loss(const float* __restrict__ nll, const float* __restrict__ msk,
                       float* __restrict__ out) {
  int tid = threadIdx.x;
  __shared__ float r1[256], r2[256];
  float a = 0.0f, b = 0.0f;
  for (int i = tid; i < LSEQ; i += 256) { a += nll[i]; b += msk[i]; }
  r1[tid] = a; r2[tid] = b; __syncthreads();
  for (int o = 128; o > 0; o >>= 1) {
    if (tid < o) { r1[tid] += r1[tid + o]; r2[tid] += r2[tid + o]; }
    __syncthreads();
  }
  if (tid == 0) out[0] = r1[0] / fmaxf(r2[0], 1.0f);
}

// =============================================================================
extern "C" void kernel_launch(void* const* d_in, const int* in_sizes, int n_in,
                              void* d_out, int out_size, void* d_ws, size_t ws_size,
                              hipStream_t stream) {
  const int*   idx    = (const int*)d_in[0];
  const int*   tgt    = (const int*)d_in[1];
  const float* emb    = (const float*)d_in[2];
  const float* norm_w = (const float*)d_in[3];
  const float* in_w   = (const float*)d_in[4];
  const float* conv_w = (const float*)d_in[5];
  const float* conv_b = (const float*)d_in[6];
  const float* xp_w   = (const float*)d_in[7];
  const float* dt_w   = (const float*)d_in[8];
  const float* dt_b   = (const float*)d_in[9];
  const float* a_log  = (const float*)d_in[10];
  const float* d_par  = (const float*)d_in[11];
  const float* out_w  = (const float*)d_in[12];
  const float* normf  = (const float*)d_in[13];

  float* logits = (float*)d_out;
  float* loss   = logits + (size_t)LSEQ * VOCAB;

  char* base = (char*)d_ws;
  size_t off = 0;
  auto alloc = [&](size_t bytes) -> char* {
    char* r = base + off;
    off = (off + bytes + 255) & ~(size_t)255;
    return r;
  };
  u16*   wcat = (u16*)  alloc((size_t)TOTCVT * 2);
  float* x    = (float*)alloc((size_t)LSEQ * D_MODEL * 4);
  u16*   xnb  = (u16*)  alloc((size_t)LSEQ * D_MODEL * 2);
  u16*   xzb  = (u16*)  alloc((size_t)LSEQ * 2 * D_INNER * 2);
  u16*   xib  = (u16*)  alloc((size_t)LSEQ * D_INNER * 2);
  float* xdbl = (float*)alloc((size_t)LSEQ * 80 * 4);
  u16*   dtp  = (u16*)  alloc((size_t)LSEQ * 64 * 2);
  float* dtl  = (float*)alloc((size_t)LSEQ * D_INNER * 4);
  u16*   yb   = (u16*)  alloc((size_t)LSEQ * D_INNER * 2);
  float* pxp  = (float*)alloc((size_t)8 * LSEQ * 80 * 4);
  float* pop  = (float*)alloc((size_t)4 * LSEQ * D_MODEL * 4);
  float* apr  = (float*)alloc((size_t)NCHUNK * D_INNER * 16 * 4);
  float* hen  = (float*)alloc((size_t)NCHUNK * D_INNER * 16 * 4);
  float* hin  = (float*)alloc((size_t)NCHUNK * D_INNER * 16 * 4);
  float* nll  = (float*)alloc((size_t)LSEQ * 4);
  float* msk  = (float*)alloc((size_t)LSEQ * 4);
  float* part = pop;  // alias: logits phase runs after pop's last use
  (void)ws_size; (void)in_sizes; (void)n_in; (void)out_size;

  const u16* embb = wcat;

  k_convert_all<<<(unsigned)(TOTCVT / 256), 256, 0, stream>>>(emb, in_w, xp_w, dt_w, out_w, wcat);
  k_embed_rms<<<LSEQ, 256, 0, stream>>>(idx, emb, norm_w, x, xnb);

  for (int l = 0; l < N_LAYER; l++) {
    const u16* w1 = wcat + EMB_E + (long)l * PERL;
    const u16* w2 = w1 + W1E;
    const u16* w3 = w2 + W2E;
    const u16* w4 = w3 + W3E;

    k_gemm2<2><<<dim3(24, 16), 256, 0, stream>>>(
        xnb, w1, xzb, nullptr, 2 * D_INNER, D_MODEL, D_MODEL, D_MODEL, 2 * D_INNER);

    k_conv_silu<<<(LSEQ * D_INNER / 8) / 256, 256, 0, stream>>>(
        xzb, conv_w + (long)l * D_INNER * 4, conv_b + l * D_INNER, xib);

    k_gemm_part<<<dim3(1, 16, 8), 256, 0, stream>>>(
        xib, w2, pxp, 80, D_INNER / 8, D_INNER, D_INNER, 80);
    k_red_xd<<<(LSEQ * 128) / 256, 256, 0, stream>>>(pxp, xdbl, dtp);

    k_gemm2<1><<<dim3(12, 16), 256, 0, stream>>>(
        dtp, w3, dtl, dt_b + l * D_INNER, D_INNER, 64, 64, 64, D_INNER);

    const float* al = a_log + (long)l * D_INNER * D_STATE;
    k_scanA<<<dim3(D_INNER / 256, NCHUNK), 256, 0, stream>>>(dtl, xib, xdbl, al, apr, hen);
    k_scanB<<<(D_INNER * 16) / 256, 256, 0, stream>>>(apr, hen, hin);
    k_scanC<<<dim3(D_INNER / 256, NCHUNK), 256, 0, stream>>>(
        dtl, xib, xdbl, al, hin, d_par + l * D_INNER, xzb, yb);

    k_gemm_part<<<dim3(6, 16, 4), 256, 0, stream>>>(
        yb, w4, pop, D_MODEL, D_INNER / 4, D_INNER, D_INNER, D_MODEL);

    const float* wn = (l < N_LAYER - 1) ? (norm_w + (l + 1) * D_MODEL) : normf;
    k_rms_red<<<LSEQ, 256, 0, stream>>>(pop, wn, x, xnb);
  }

  k_gemm_logits<<<400 * 8, 256, 0, stream>>>(xnb, embb, logits, part);
  k_lse_final<<<LSEQ / 256, 256, 0, stream>>>(part, logits, tgt, nll, msk);
  k_loss<<<1, 256, 0, stream>>>(nll, msk, loss);
}